// Round 3
// baseline (511.025 us; speedup 1.0000x reference)
//
#include <hip/hip_runtime.h>

typedef unsigned short u16;
typedef __attribute__((ext_vector_type(8))) short short8;
typedef __attribute__((ext_vector_type(4))) float floatx4;
typedef __attribute__((ext_vector_type(4))) unsigned short ushort4_t;

#define S_LEN 2048
#define DMODEL 1024
#define NHEAD 16
#define HDIM 64

__device__ __forceinline__ u16 f2bf(float f) {
    union { float f; unsigned u; } v; v.f = f;
    unsigned u = v.u;
    unsigned r = (u + 0x7fffu + ((u >> 16) & 1u)) >> 16;
    return (u16)r;
}

// round-half-up bf16 pack (2 VALU ops) — for GEMM-feeding intermediates
__device__ __forceinline__ u16 f2bf_fast(float f) {
    union { float f; unsigned u; } v; v.f = f;
    return (u16)((v.u + 0x8000u) >> 16);
}

__device__ __forceinline__ void gld_lds16(const u16* g, u16* l) {
    __builtin_amdgcn_global_load_lds((const __attribute__((address_space(1))) void*)g,
                                     (__attribute__((address_space(3))) void*)l,
                                     16, 0, 0);
}

// ---------------- LayerNorm -> bf16 ----------------
__global__ __launch_bounds__(256) void ln_kernel(
    const float* __restrict__ x, const float* __restrict__ g,
    const float* __restrict__ b, u16* __restrict__ out)
{
    int row = blockIdx.x;
    int tid = threadIdx.x;
    const float4* xr = (const float4*)(x + (size_t)row * DMODEL);
    float4 v = xr[tid];
    float s  = v.x + v.y + v.z + v.w;
    float s2 = v.x * v.x + v.y * v.y + v.z * v.z + v.w * v.w;
    #pragma unroll
    for (int off = 1; off < 64; off <<= 1) {
        s  += __shfl_xor(s, off, 64);
        s2 += __shfl_xor(s2, off, 64);
    }
    __shared__ float red[2][4];
    int w = tid >> 6, lane = tid & 63;
    if (lane == 0) { red[0][w] = s; red[1][w] = s2; }
    __syncthreads();
    s  = red[0][0] + red[0][1] + red[0][2] + red[0][3];
    s2 = red[1][0] + red[1][1] + red[1][2] + red[1][3];
    float mu  = s * (1.0f / DMODEL);
    float var = s2 * (1.0f / DMODEL) - mu * mu;
    float inv = rsqrtf(var + 1e-5f);
    const float4* gr = (const float4*)g;
    const float4* br = (const float4*)b;
    float4 gv = gr[tid], bv = br[tid];
    u16* o = out + (size_t)row * DMODEL + tid * 4;
    o[0] = f2bf((v.x - mu) * inv * gv.x + bv.x);
    o[1] = f2bf((v.y - mu) * inv * gv.y + bv.y);
    o[2] = f2bf((v.z - mu) * inv * gv.z + bv.z);
    o[3] = f2bf((v.w - mu) * inv * gv.w + bv.w);
}

// ---------------- weight transpose + cast: wt[n][k] = bf16(w[k][n]) ----------------
__global__ __launch_bounds__(256) void transpose_cast(
    const float* __restrict__ w, u16* __restrict__ wt, int K, int N)
{
    __shared__ float t[32][33];
    int n0 = blockIdx.x * 32, k0 = blockIdx.y * 32;
    int x = threadIdx.x, y = threadIdx.y;
    #pragma unroll
    for (int j = y; j < 32; j += 8)
        t[j][x] = w[(size_t)(k0 + j) * N + n0 + x];
    __syncthreads();
    #pragma unroll
    for (int j = y; j < 32; j += 8)
        wt[(size_t)(n0 + j) * K + k0 + x] = f2bf(t[x][j]);
}

// ---------------- legacy 128^2 GEMM (kept for N=1024 GEMMs: AO, FC2) ----------------
// MODE 1/3: fout = C + bias + res (fp32)
template<int MODE>
__global__ __launch_bounds__(256) void gemm_bt(
    const u16* __restrict__ A, const u16* __restrict__ BT,
    int M, int N, int K,
    const float* __restrict__ bias, const float* __restrict__ res,
    float* __restrict__ fout,
    u16* __restrict__ o0, u16* __restrict__ o1, u16* __restrict__ o2)
{
    __shared__ __attribute__((aligned(16))) u16 As[2][128 * 64];
    __shared__ __attribute__((aligned(16))) u16 Bs[2][128 * 64];
    int tid = threadIdx.x;
    int lane = tid & 63, w = tid >> 6;
    int wm = (w >> 1) * 64, wn = (w & 1) * 64;
    int l15 = lane & 15, quad = lane >> 4;
    int rowBase = blockIdx.y * 128, colBase = blockIdx.x * 128;

    floatx4 acc[4][4] = {};

    const u16* pa[4];
    const u16* pbt[4];
    int scb[4];
    #pragma unroll
    for (int i = 0; i < 4; ++i) {
        int c  = i * 256 + tid;
        int r  = c >> 3;
        int cs = ((c & 7) ^ (r & 7)) * 8;            // swizzled source chunk
        pa[i]  = A  + (size_t)(rowBase + r) * K + cs;
        pbt[i] = BT + (size_t)(colBase + r) * K + cs;
        scb[i] = (i * 256 + (tid & 0xC0)) * 8;       // wave-uniform LDS base
    }

    int KT = K >> 6;

    #pragma unroll
    for (int i = 0; i < 4; ++i) {
        gld_lds16(pa[i],  &As[0][0] + scb[i]);
        gld_lds16(pbt[i], &Bs[0][0] + scb[i]);
    }

    for (int kt = 0; kt < KT; ++kt) {
        __syncthreads();

        if (kt + 1 < KT) {
            u16* abuf = &As[(kt + 1) & 1][0];
            u16* bbuf = &Bs[(kt + 1) & 1][0];
            #pragma unroll
            for (int i = 0; i < 4; ++i) {
                pa[i]  += 64;
                pbt[i] += 64;
                gld_lds16(pa[i],  abuf + scb[i]);
                gld_lds16(pbt[i], bbuf + scb[i]);
            }
        }

        const u16* as = &As[kt & 1][0];
        const u16* bs = &Bs[kt & 1][0];
        #pragma unroll
        for (int ks = 0; ks < 2; ++ks) {
            int sw = (((ks * 4 + quad) ^ (l15 & 7))) * 8;
            short8 af[4], bf[4];
            #pragma unroll
            for (int im = 0; im < 4; ++im)
                af[im] = *(const short8*)(as + (wm + im * 16 + l15) * 64 + sw);
            #pragma unroll
            for (int in = 0; in < 4; ++in)
                bf[in] = *(const short8*)(bs + (wn + in * 16 + l15) * 64 + sw);
            #pragma unroll
            for (int im = 0; im < 4; ++im)
                #pragma unroll
                for (int in = 0; in < 4; ++in)
                    acc[im][in] = __builtin_amdgcn_mfma_f32_16x16x32_bf16(af[im], bf[in], acc[im][in], 0, 0, 0);
        }
    }

    #pragma unroll
    for (int im = 0; im < 4; ++im) {
        #pragma unroll
        for (int in = 0; in < 4; ++in) {
            #pragma unroll
            for (int r = 0; r < 4; ++r) {
                int gr = rowBase + wm + im * 16 + quad * 4 + r;
                int gc = colBase + wn + in * 16 + l15;
                float v = acc[im][in][r] + bias[gc];
                fout[(size_t)gr * N + gc] = v + res[(size_t)gr * N + gc];
            }
        }
    }
}

// ---------------- 256^2 8-phase GEMM (T3+T4 counted-vmcnt + T5) ----------------
// BM=BN=256, BK=64, 8 waves (2M x 4N), 512 thr, LDS 128 KiB (2 dbuf x 2 half x A,B).
// Per phase: {ds_read subtile || stage 1 half-tile ; barrier ; lgkmcnt(0) ;
//             setprio(1) 16xMFMA setprio(0) ; barrier}. vmcnt(4) at ph4/ph8 only.
// Stage ledger (verified): ph1 A0(t+1) ph2 A1(t+1) ph3 B0(t+2) ph4 B1(t+2)
//                          ph5 A0(t+2) ph6 A1(t+2) ph7 B0(t+3) ph8 B1(t+3)
//  - B slots freed after ph2/ph6 (last B ds_read), A slots after ph3/ph7.
//  - vmcnt(4) => newest 2 stage-phases may be in flight; every half-tile lands
//    >=2 phases before first read. Last iter prefetches clamp to KT-1 (freed
//    slots, never read, L2-hot) so counts stay uniform.
// MODE 0: QKV scatter (Q *0.125, K, V direct-transposed).  MODE 2: GELU->bf16.
template<int MODE>
__global__ __launch_bounds__(512, 2) void gemm256(
    const u16* __restrict__ A, const u16* __restrict__ BT,
    int M, int N, int K,
    const float* __restrict__ bias,
    u16* __restrict__ o0, u16* __restrict__ o1)
{
    __shared__ __attribute__((aligned(16))) u16 As[2][2][128 * 64];
    __shared__ __attribute__((aligned(16))) u16 Bs[2][2][128 * 64];
    int tid = threadIdx.x;
    int lane = tid & 63, w = tid >> 6;
    int wrow = w >> 2, wcol = w & 3;
    int l15 = lane & 15, quad = lane >> 4;
    int rowBase = blockIdx.y * 256, colBase = blockIdx.x * 256;
    int nrb = (wcol & 1) * 64;

    int swz[2] = { (quad ^ (l15 & 7)) * 8, ((4 + quad) ^ (l15 & 7)) * 8 };

    // staging precompute (32-bit offsets; max ~8.4M elements)
    int cid0 = tid, cid1 = 512 + tid;
    int r0 = cid0 >> 3, r1 = cid1 >> 3;
    unsigned cs0 = (unsigned)(((cid0 & 7) ^ (r0 & 7)) * 8);
    unsigned cs1 = (unsigned)(((cid1 & 7) ^ (r1 & 7)) * 8);
    unsigned aoff0 = (unsigned)((rowBase + r0) * K) + cs0;
    unsigned aoff1 = (unsigned)((rowBase + r1) * K) + cs1;
    unsigned boff0 = (unsigned)((colBase + r0) * K) + cs0;
    unsigned boff1 = (unsigned)((colBase + r1) * K) + cs1;
    unsigned ldo0 = (unsigned)(cid0 * 8), ldo1 = (unsigned)(cid1 * 8);
    unsigned hK = (unsigned)(128 * K);

    floatx4 acc[8][4] = {};
    short8 af[4][2], bfL[2][2], bfH[2][2];

    int KT = K >> 6;

#define STG_A(db, tt, h) do { unsigned tb_ = (unsigned)(tt) * 64u + (h) * hK;      \
    gld_lds16(A + aoff0 + tb_, &As[db][h][0] + ldo0);                              \
    gld_lds16(A + aoff1 + tb_, &As[db][h][0] + ldo1); } while (0)
#define STG_B(db, tt, h) do { unsigned tb_ = (unsigned)(tt) * 64u + (h) * hK;      \
    gld_lds16(BT + boff0 + tb_, &Bs[db][h][0] + ldo0);                             \
    gld_lds16(BT + boff1 + tb_, &Bs[db][h][0] + ldo1); } while (0)
#define LDS_A(buf, MFB) do { const u16* ap_ = &As[buf][wrow][0];                   \
    _Pragma("unroll") for (int m_ = 0; m_ < 4; ++m_) {                             \
      af[m_][0] = *(const short8*)(ap_ + (((MFB) + m_) * 16 + l15) * 64 + swz[0]); \
      af[m_][1] = *(const short8*)(ap_ + (((MFB) + m_) * 16 + l15) * 64 + swz[1]); } } while (0)
#define LDS_B(buf, NFP, dst) do { const u16* bp_ = &Bs[buf][wcol >> 1][0];         \
    _Pragma("unroll") for (int n_ = 0; n_ < 2; ++n_) {                             \
      dst[n_][0] = *(const short8*)(bp_ + (nrb + ((NFP) * 2 + n_) * 16 + l15) * 64 + swz[0]); \
      dst[n_][1] = *(const short8*)(bp_ + (nrb + ((NFP) * 2 + n_) * 16 + l15) * 64 + swz[1]); } } while (0)
#define MFMA_Q(MFB, NFP, bsrc) do { __builtin_amdgcn_s_setprio(1);                 \
    _Pragma("unroll") for (int m_ = 0; m_ < 4; ++m_)                               \
    _Pragma("unroll") for (int n_ = 0; n_ < 2; ++n_) {                             \
      acc[(MFB) + m_][(NFP) * 2 + n_] = __builtin_amdgcn_mfma_f32_16x16x32_bf16(af[m_][0], bsrc[n_][0], acc[(MFB) + m_][(NFP) * 2 + n_], 0, 0, 0); \
      acc[(MFB) + m_][(NFP) * 2 + n_] = __builtin_amdgcn_mfma_f32_16x16x32_bf16(af[m_][1], bsrc[n_][1], acc[(MFB) + m_][(NFP) * 2 + n_], 0, 0, 0); } \
    __builtin_amdgcn_s_setprio(0); } while (0)
#define PH_MID() do { __builtin_amdgcn_s_barrier();                                \
    asm volatile("s_waitcnt lgkmcnt(0)" ::: "memory"); } while (0)
#define PH_END() __builtin_amdgcn_s_barrier()

    // prologue: tile0 full + tile1 B-halves; wait tile0 landed (B(1) may fly)
    STG_A(0, 0, 0); STG_A(0, 0, 1);
    STG_B(0, 0, 0); STG_B(0, 0, 1);
    STG_B(1, 1, 0); STG_B(1, 1, 1);
    asm volatile("s_waitcnt vmcnt(4)" ::: "memory");
    __builtin_amdgcn_s_barrier();

    for (int t = 0; t < KT; t += 2) {
        int t2 = (t + 2 < KT) ? t + 2 : KT - 1;
        int t3 = (t + 3 < KT) ? t + 3 : KT - 1;

        // ph1: tile t (buf0) Q(M0-3,N0-1); stage A0(t+1)
        LDS_A(0, 0); LDS_B(0, 0, bfL);
        STG_A(1, t + 1, 0);
        PH_MID(); MFMA_Q(0, 0, bfL); PH_END();

        // ph2: Q(M0-3,N2-3); stage A1(t+1)
        LDS_B(0, 1, bfH);
        STG_A(1, t + 1, 1);
        PH_MID(); MFMA_Q(0, 1, bfH); PH_END();

        // ph3: Q(M4-7,N2-3); stage B0(t+2)
        LDS_A(0, 4);
        STG_B(0, t2, 0);
        PH_MID(); MFMA_Q(4, 1, bfH); PH_END();

        // ph4: Q(M4-7,N0-1); stage B1(t+2); counted vmcnt
        STG_B(0, t2, 1);
        asm volatile("s_waitcnt vmcnt(4)" ::: "memory");
        PH_MID(); MFMA_Q(4, 0, bfL); PH_END();

        // ph5: tile t+1 (buf1) Q(M0-3,N0-1); stage A0(t+2)
        LDS_A(1, 0); LDS_B(1, 0, bfL);
        STG_A(0, t2, 0);
        PH_MID(); MFMA_Q(0, 0, bfL); PH_END();

        // ph6: Q(M0-3,N2-3); stage A1(t+2)
        LDS_B(1, 1, bfH);
        STG_A(0, t2, 1);
        PH_MID(); MFMA_Q(0, 1, bfH); PH_END();

        // ph7: Q(M4-7,N2-3); stage B0(t+3)
        LDS_A(1, 4);
        STG_B(1, t3, 0);
        PH_MID(); MFMA_Q(4, 1, bfH); PH_END();

        // ph8: Q(M4-7,N0-1); stage B1(t+3); counted vmcnt
        STG_B(1, t3, 1);
        asm volatile("s_waitcnt vmcnt(4)" ::: "memory");
        PH_MID(); MFMA_Q(4, 0, bfL); PH_END();
    }
    asm volatile("s_waitcnt vmcnt(0)" ::: "memory");

#undef STG_A
#undef STG_B
#undef LDS_A
#undef LDS_B
#undef MFMA_Q
#undef PH_MID
#undef PH_END

    // epilogue
    int wr0 = rowBase + wrow * 128 + quad * 4;
    int wc0 = colBase + wcol * 64 + l15;
    if (MODE == 0) {
        int t = colBase >> 10;                    // uniform per block (q/k/v)
        int cb1023 = (colBase & 1023) + wcol * 64;
        if (t == 2) {
            // V: write directly transposed [BH,64,S]; r=0..3 are consecutive s
            #pragma unroll
            for (int mf = 0; mf < 8; ++mf) {
                int gr0 = wr0 + mf * 16;
                int bb2 = gr0 >> 11, ss = gr0 & 2047;
                #pragma unroll
                for (int nf = 0; nf < 4; ++nf) {
                    int gc = wc0 + nf * 16;
                    int rr = cb1023 + nf * 16 + l15;
                    int hh = rr >> 6, hd = rr & 63;
                    float bv = bias[gc];
                    ushort4_t pk;
                    pk.x = f2bf_fast(acc[mf][nf][0] + bv);
                    pk.y = f2bf_fast(acc[mf][nf][1] + bv);
                    pk.z = f2bf_fast(acc[mf][nf][2] + bv);
                    pk.w = f2bf_fast(acc[mf][nf][3] + bv);
                    *(ushort4_t*)(o1 + ((size_t)(bb2 * NHEAD + hh) * HDIM + hd) * S_LEN + ss) = pk;
                }
            }
        } else {
            u16* qb = o0 + (size_t)t * 8388608;    // 8192*1024 elements per tensor
            float sc = (t == 0) ? 0.125f : 1.0f;   // fold softmax 1/sqrt(64) into Q
            #pragma unroll
            for (int mf = 0; mf < 8; ++mf) {
                #pragma unroll
                for (int nf = 0; nf < 4; ++nf) {
                    int gc = wc0 + nf * 16;
                    int rr = cb1023 + nf * 16 + l15;
                    int hh = rr >> 6, hd = rr & 63;
                    #pragma unroll
                    for (int r = 0; r < 4; ++r) {
                        int gr = wr0 + mf * 16 + r;
                        float v = (acc[mf][nf][r] + bias[gc]) * sc;
                        int bb2 = gr >> 11, ss = gr & 2047;
                        qb[(((size_t)(bb2 * NHEAD + hh) * S_LEN + ss) * HDIM) + hd] = f2bf_fast(v);
                    }
                }
            }
        }
    } else {
        // MODE 2: GELU -> bf16 row-major
        #pragma unroll
        for (int mf = 0; mf < 8; ++mf) {
            #pragma unroll
            for (int nf = 0; nf < 4; ++nf) {
                int gc = wc0 + nf * 16;
                float bv = bias[gc];
                #pragma unroll
                for (int r = 0; r < 4; ++r) {
                    int gr = wr0 + mf * 16 + r;
                    float v = acc[mf][nf][r] + bv;
                    float p = v * (1.59576912f + 0.07135481f * v * v);
                    float e = __expf(-p);
                    float gl = v * __builtin_amdgcn_rcpf(1.0f + e);
                    o0[(size_t)gr * N + gc] = f2bf_fast(gl);
                }
            }
        }
    }
}

// ---------------- flash attention (causal), bf16 in/out ----------------
// Fixed-max softmax (scale pre-folded into Q). Macro Q-tile = 128 rows/block;
// each wave owns TWO 16-row strips 64 apart, so every K/V ds_read_b128 feeds
// MFMAs for 32 q-rows. Blocks handle macros {p, 15-p} -> 34 K-iters each.
// Grid (bh=64, p=8): ID%8 = bh%8 -> all p-blocks of one head share one XCD L2.
__global__ __launch_bounds__(256) void flash_attn(
    const u16* __restrict__ Q, const u16* __restrict__ Kb,
    const u16* __restrict__ Vt, u16* __restrict__ O)
{
    __shared__ __attribute__((aligned(16))) u16 Ks[2][64 * 64];
    __shared__ __attribute__((aligned(16))) u16 Vs[2][64 * 64];
    __shared__ __attribute__((aligned(16))) u16 Pl[4][2][16][64];
    int tid = threadIdx.x;
    int lane = tid & 63, w = tid >> 6;
    int l15 = lane & 15, quad = lane >> 4;
    int bh = blockIdx.x;           // 0..63 (fastest-varying -> XCD = bh%8)
    int pp = blockIdx.y;           // 0..7
    int bb = bh >> 4, h = bh & 15;

    const u16* Kp0 = Kb + (size_t)bh * S_LEN * HDIM;
    const u16* Vp  = Vt + (size_t)bh * HDIM * S_LEN;

    int rstage = lane >> 3;                       // 0..7
    int cstage = ((lane & 7) ^ rstage) * 8;       // swizzled source chunk (u16 units)
    int vrow0  = w * 8 + rstage;                  // staging row within 32-row half

    int ms[2] = {pp, 15 - pp};
    int pb = 0;

    // prologue: stage K/V tile kt=0 into parity 0
    #pragma unroll
    for (int i = 0; i < 2; ++i) {
        int row = i * 32 + vrow0;
        gld_lds16(Kp0 + row * HDIM + cstage, &Ks[0][0] + i * 2048 + w * 512);
        gld_lds16(Vp + (size_t)row * S_LEN + cstage, &Vs[0][0] + i * 2048 + w * 512);
    }

    #pragma unroll 1
    for (int sel = 0; sel < 2; ++sel) {
        int m = ms[sel];
        int q0 = m * 128;

        // Q fragments for both strips (strip1 = +64 rows)
        const u16* Qp = Q + ((size_t)bh * S_LEN + q0 + w * 16) * HDIM;
        short8 aq0[2], aq1[2];
        #pragma unroll
        for (int ks = 0; ks < 2; ++ks) {
            aq0[ks] = *(const short8*)(Qp + l15 * HDIM + ks * 32 + quad * 8);
            aq1[ks] = *(const short8*)(Qp + 64 * HDIM + l15 * HDIM + ks * 32 + quad * 8);
        }

        floatx4 acc_o0[4] = {}, acc_o1[4] = {};
        float rs0[4] = {0.f, 0.f, 0.f, 0.f};
        float rs1[4] = {0.f, 0.f, 0.f, 0.f};

        int KT = 2 * m + 2;   // K-tiles this macro (strip1 needs kt <= 2m+1)

        auto softmax_store = [&](floatx4 (&sa)[4], float (&rs)[4], int st, bool diag) {
            #pragma unroll
            for (int nt = 0; nt < 4; ++nt) {
                int wc = nt * 16 + l15;
                int wchunk = wc >> 3, woff = wc & 7;
                #pragma unroll
                for (int r = 0; r < 4; ++r) {
                    float sv = sa[nt][r];           // scale already folded into Q
                    if (diag) {
                        int qr = w * 16 + quad * 4 + r;
                        if (wc > qr) sv = -1e30f;
                    }
                    float pv = __expf(sv);          // fixed-max softmax; exp(-1e30)=0
                    rs[r] += pv;
                    int row = quad * 4 + r;
                    Pl[w][st][row][((wchunk ^ (row & 7)) << 3) + woff] = f2bf_fast(pv);
                }
            }
        };

        #pragma unroll 1
        for (int kt = 0; kt < KT; ++kt) {
            __syncthreads();   // tile kt (parity pb) resident; drain covered by prior phase
            int cur = pb;

            // prefetch next tile: kt+1, or next macro's kt=0
            int nk = (kt + 1 < KT) ? (kt + 1) : ((sel < 1) ? 0 : -1);
            if (nk >= 0) {
                pb ^= 1;
                const u16* Kg = Kp0 + (size_t)nk * 64 * HDIM;
                const u16* Vg = Vp + nk * 64;
                u16* kb_ = &Ks[pb][0];
                u16* vb_ = &Vs[pb][0];
                #pragma unroll
                for (int i = 0; i < 2; ++i) {
                    int row = i * 32 + vrow0;
                    gld_lds16(Kg + row * HDIM + cstage, kb_ + i * 2048 + w * 512);
                    gld_lds16(Vg + (size_t)row * S_LEN + cstage, vb_ + i * 2048 + w * 512);
                }
            }

            const u16* kcur = &Ks[cur][0];
            const u16* vcur = &Vs[cur][0];

            bool a0 = (kt < KT - 1);      // strip0 active (kt <= 2m)

            // QK^T: shared K-frag reads feed both strips
            floatx4 s0a[4] = {}, s1a[4] = {};
            __builtin_amdgcn_s_setprio(1);
            #pragma unroll
            for (int nt = 0; nt < 4; ++nt) {
                #pragma unroll
                for (int ks = 0; ks < 2; ++ks) {
                    int sw = ((ks * 4 + quad) ^ (l15 & 7)) * 8;
                    short8 bk = *(const short8*)(kcur + (nt * 16 + l15) * 64 + sw);
                    s0a[nt] = __builtin_amdgcn_mfma_f32_16x16x32_bf16(aq0[ks], bk, s0a[nt], 0, 0, 0);
                    s1a[nt] = __builtin_amdgcn_mfma_f32_16x16x32_bf16(aq1[ks], bk, s1a[nt], 0, 0, 0);
                }
            }
            __builtin_amdgcn_s_setprio(0);

            if (a0) softmax_store(s0a, rs0, 0, kt == KT - 2);
            softmax_store(s1a, rs1, 1, kt == KT - 1);

            // per-wave LDS round-trip: same-wave DS ordering, no barrier needed
            short8 pf0[2] = {}, pf1[2];
            if (a0) {
                #pragma unroll
                for (int ks = 0; ks < 2; ++ks) {
                    int pc = ((ks * 4 + quad) ^ (l15 & 7)) * 8;
                    pf0[ks] = *(const short8*)(&Pl[w][0][l15][pc]);
                }
            }
            #pragma unroll
            for (int ks = 0; ks < 2; ++ks) {
                int pc = ((ks * 4 + quad) ^ (l15 & 7)) * 8;
                pf1[ks] = *(const short8*)(&Pl[w][1][l15][pc]);
            }

            // PV: shared V-frag reads feed both strips (pf0 zeroed when inactive)
            __builtin_amdgcn_s_setprio(1);
            #pragma unroll
            for (int nt = 0; nt < 4; ++nt) {
                #pragma unroll
                for (int ks = 0; ks < 2; ++ks) {
                    int sw = ((ks * 4 + quad) ^ (l15 & 7)) * 8;
                    short8 bv = *(const short8*)(vcur + (nt * 16 + l15) * 64 + sw);
                    acc_o0[nt] = __builtin_amdgcn_mfma_f32_16x16x32_bf16(pf0[ks], bv, acc_o0[nt], 0, 0, 0);
                    acc_o1[nt] = __builtin_amdgcn_mfma_f32_16x16x32_bf16(pf1[ks], bv, acc_o1[nt], 0, 0, 0);
                }
            }
            __builtin_amdgcn_s_setprio(0);
        }

        float inv0[4], inv1[4];
        #pragma unroll
        for (int r = 0; r < 4; ++r) {
            float sm0 = rs0[r], sm1 = rs1[r];
            #pragma unroll
            for (int off = 1; off < 16; off <<= 1) {
                sm0 += __shfl_xor(sm0, off, 64);
                sm1 += __shfl_xor(sm1, off, 64);
            }
            inv0[r] = 1.0f / sm0;
            inv1[r] = 1.0f / sm1;
        }

        #pragma unroll
        for (int nt = 0; nt < 4; ++nt) {
            #pragma unroll
            for (int r = 0; r < 4; ++r) {
                int qr = q0 + w * 16 + quad * 4 + r;
                int hd = nt * 16 + l15;
                O[((size_t)bb * S_LEN + qr) * DMODEL + h * HDIM + hd] = f2bf(acc_o0[nt][r] * inv0[r]);
                O[((size_t)bb * S_LEN + qr + 64) * DMODEL + h * HDIM + hd] = f2bf(acc_o1[nt][r] * inv1[r]);
            }
        }
    }
}

extern "C" void kernel_launch(void* const* d_in, const int* in_sizes, int n_in,
                              void* d_out, int out_size, void* d_ws, size_t ws_size,
                              hipStream_t stream)
{
    const float* x    = (const float*)d_in[0];
    const float* ln1g = (const float*)d_in[2];
    const float* ln1b = (const float*)d_in[3];
    const float* wqkv = (const float*)d_in[4];
    const float* bqkv = (const float*)d_in[5];
    const float* wao  = (const float*)d_in[6];
    const float* bao  = (const float*)d_in[7];
    const float* ln2g = (const float*)d_in[8];
    const float* ln2b = (const float*)d_in[9];
    const float* wfc  = (const float*)d_in[10];
    const float* bfc  = (const float*)d_in[11];
    const float* wout = (const float*)d_in[12];
    const float* bout = (const float*)d_in[13];
    float* out = (float*)d_out;

    char* ws = (char*)d_ws;
    u16* wqkvT = (u16*)(ws + 0);          //  6.3 MB
    u16* waoT  = (u16*)(ws + 6291456);    //  2.1 MB
    u16* wfcT  = (u16*)(ws + 8388608);    //  8.4 MB
    u16* woutT = (u16*)(ws + 16777216);   //  8.4 MB
    u16* hb    = (u16*)(ws + 25165824);   // 16.8 MB: LN1 out; attn out; later h2
    u16* QKVb  = (u16*)(ws + 41943040);   // 50.3 MB: Q|K each 8.4M elements (V slot unused)
    u16* Vtb   = (u16*)(ws + 92274688);   // 16.8 MB: V^T (written directly by gemm256<0>)
    u16* Gb    = (u16*)(ws + 41943040);   // 67.1 MB: GELU out (QKV+Vt dead by then)

    u16* Qb   = QKVb;
    u16* Kbuf = QKVb + 8388608;

    transpose_cast<<<dim3(3072/32, 1024/32), dim3(32, 8), 0, stream>>>(wqkv, wqkvT, 1024, 3072);
    transpose_cast<<<dim3(1024/32, 1024/32), dim3(32, 8), 0, stream>>>(wao,  waoT,  1024, 1024);
    transpose_cast<<<dim3(4096/32, 1024/32), dim3(32, 8), 0, stream>>>(wfc,  wfcT,  1024, 4096);
    transpose_cast<<<dim3(1024/32, 4096/32), dim3(32, 8), 0, stream>>>(wout, woutT, 4096, 1024);

    ln_kernel<<<8192, 256, 0, stream>>>(x, ln1g, ln1b, hb);

    gemm256<0><<<dim3(3072/256, 8192/256), 512, 0, stream>>>(
        hb, wqkvT, 8192, 3072, 1024, bqkv, QKVb, Vtb);

    flash_attn<<<dim3(64, 8), 256, 0, stream>>>(Qb, Kbuf, Vtb, hb);

    gemm_bt<1><<<dim3(1024/128, 8192/128), 256, 0, stream>>>(
        hb, waoT, 8192, 1024, 1024, bao, x, out, nullptr, nullptr, nullptr);

    ln_kernel<<<8192, 256, 0, stream>>>(out, ln2g, ln2b, hb);

    gemm256<2><<<dim3(4096/256, 8192/256), 512, 0, stream>>>(
        hb, wfcT, 8192, 4096, 1024, bfc, Gb, nullptr);

    gemm_bt<3><<<dim3(1024/128, 8192/128), 256, 0, stream>>>(
        Gb, woutT, 8192, 1024, 4096, bout, out, out, nullptr, nullptr, nullptr);
}

// Round 5
// 509.206 us; speedup vs baseline: 1.0036x; 1.0036x over previous
//
#include <hip/hip_runtime.h>

typedef unsigned short u16;
typedef __attribute__((ext_vector_type(8))) short short8;
typedef __attribute__((ext_vector_type(4))) float floatx4;
typedef __attribute__((ext_vector_type(4))) unsigned short ushort4_t;

#define S_LEN 2048
#define DMODEL 1024
#define NHEAD 16
#define HDIM 64

__device__ __forceinline__ u16 f2bf(float f) {
    union { float f; unsigned u; } v; v.f = f;
    unsigned u = v.u;
    unsigned r = (u + 0x7fffu + ((u >> 16) & 1u)) >> 16;
    return (u16)r;
}

// round-half-up bf16 pack (2 VALU ops) — for GEMM-feeding intermediates
__device__ __forceinline__ u16 f2bf_fast(float f) {
    union { float f; unsigned u; } v; v.f = f;
    return (u16)((v.u + 0x8000u) >> 16);
}

__device__ __forceinline__ void gld_lds16(const u16* g, u16* l) {
    __builtin_amdgcn_global_load_lds((const __attribute__((address_space(1))) void*)g,
                                     (__attribute__((address_space(3))) void*)l,
                                     16, 0, 0);
}

// ---------------- LayerNorm -> bf16 ----------------
__global__ __launch_bounds__(256) void ln_kernel(
    const float* __restrict__ x, const float* __restrict__ g,
    const float* __restrict__ b, u16* __restrict__ out)
{
    int row = blockIdx.x;
    int tid = threadIdx.x;
    const float4* xr = (const float4*)(x + (size_t)row * DMODEL);
    float4 v = xr[tid];
    float s  = v.x + v.y + v.z + v.w;
    float s2 = v.x * v.x + v.y * v.y + v.z * v.z + v.w * v.w;
    #pragma unroll
    for (int off = 1; off < 64; off <<= 1) {
        s  += __shfl_xor(s, off, 64);
        s2 += __shfl_xor(s2, off, 64);
    }
    __shared__ float red[2][4];
    int w = tid >> 6, lane = tid & 63;
    if (lane == 0) { red[0][w] = s; red[1][w] = s2; }
    __syncthreads();
    s  = red[0][0] + red[0][1] + red[0][2] + red[0][3];
    s2 = red[1][0] + red[1][1] + red[1][2] + red[1][3];
    float mu  = s * (1.0f / DMODEL);
    float var = s2 * (1.0f / DMODEL) - mu * mu;
    float inv = rsqrtf(var + 1e-5f);
    const float4* gr = (const float4*)g;
    const float4* br = (const float4*)b;
    float4 gv = gr[tid], bv = br[tid];
    u16* o = out + (size_t)row * DMODEL + tid * 4;
    o[0] = f2bf((v.x - mu) * inv * gv.x + bv.x);
    o[1] = f2bf((v.y - mu) * inv * gv.y + bv.y);
    o[2] = f2bf((v.z - mu) * inv * gv.z + bv.z);
    o[3] = f2bf((v.w - mu) * inv * gv.w + bv.w);
}

// ---------------- weight transpose + cast: wt[n][k] = bf16(w[k][n]) ----------------
__global__ __launch_bounds__(256) void transpose_cast(
    const float* __restrict__ w, u16* __restrict__ wt, int K, int N)
{
    __shared__ float t[32][33];
    int n0 = blockIdx.x * 32, k0 = blockIdx.y * 32;
    int x = threadIdx.x, y = threadIdx.y;
    #pragma unroll
    for (int j = y; j < 32; j += 8)
        t[j][x] = w[(size_t)(k0 + j) * N + n0 + x];
    __syncthreads();
    #pragma unroll
    for (int j = y; j < 32; j += 8)
        wt[(size_t)(n0 + j) * K + k0 + x] = f2bf(t[x][j]);
}

// ---------------- legacy 128^2 GEMM (kept for N=1024 GEMMs: AO, FC2) ----------------
// MODE 1/3: fout = C + bias + res (fp32)
template<int MODE>
__global__ __launch_bounds__(256) void gemm_bt(
    const u16* __restrict__ A, const u16* __restrict__ BT,
    int M, int N, int K,
    const float* __restrict__ bias, const float* __restrict__ res,
    float* __restrict__ fout,
    u16* __restrict__ o0, u16* __restrict__ o1, u16* __restrict__ o2)
{
    __shared__ __attribute__((aligned(16))) u16 As[2][128 * 64];
    __shared__ __attribute__((aligned(16))) u16 Bs[2][128 * 64];
    int tid = threadIdx.x;
    int lane = tid & 63, w = tid >> 6;
    int wm = (w >> 1) * 64, wn = (w & 1) * 64;
    int l15 = lane & 15, quad = lane >> 4;
    int rowBase = blockIdx.y * 128, colBase = blockIdx.x * 128;

    floatx4 acc[4][4] = {};

    const u16* pa[4];
    const u16* pbt[4];
    int scb[4];
    #pragma unroll
    for (int i = 0; i < 4; ++i) {
        int c  = i * 256 + tid;
        int r  = c >> 3;
        int cs = ((c & 7) ^ (r & 7)) * 8;            // swizzled source chunk
        pa[i]  = A  + (size_t)(rowBase + r) * K + cs;
        pbt[i] = BT + (size_t)(colBase + r) * K + cs;
        scb[i] = (i * 256 + (tid & 0xC0)) * 8;       // wave-uniform LDS base
    }

    int KT = K >> 6;

    #pragma unroll
    for (int i = 0; i < 4; ++i) {
        gld_lds16(pa[i],  &As[0][0] + scb[i]);
        gld_lds16(pbt[i], &Bs[0][0] + scb[i]);
    }

    for (int kt = 0; kt < KT; ++kt) {
        __syncthreads();

        if (kt + 1 < KT) {
            u16* abuf = &As[(kt + 1) & 1][0];
            u16* bbuf = &Bs[(kt + 1) & 1][0];
            #pragma unroll
            for (int i = 0; i < 4; ++i) {
                pa[i]  += 64;
                pbt[i] += 64;
                gld_lds16(pa[i],  abuf + scb[i]);
                gld_lds16(pbt[i], bbuf + scb[i]);
            }
        }

        const u16* as = &As[kt & 1][0];
        const u16* bs = &Bs[kt & 1][0];
        #pragma unroll
        for (int ks = 0; ks < 2; ++ks) {
            int sw = (((ks * 4 + quad) ^ (l15 & 7))) * 8;
            short8 af[4], bf[4];
            #pragma unroll
            for (int im = 0; im < 4; ++im)
                af[im] = *(const short8*)(as + (wm + im * 16 + l15) * 64 + sw);
            #pragma unroll
            for (int in = 0; in < 4; ++in)
                bf[in] = *(const short8*)(bs + (wn + in * 16 + l15) * 64 + sw);
            #pragma unroll
            for (int im = 0; im < 4; ++im)
                #pragma unroll
                for (int in = 0; in < 4; ++in)
                    acc[im][in] = __builtin_amdgcn_mfma_f32_16x16x32_bf16(af[im], bf[in], acc[im][in], 0, 0, 0);
        }
    }

    #pragma unroll
    for (int im = 0; im < 4; ++im) {
        #pragma unroll
        for (int in = 0; in < 4; ++in) {
            #pragma unroll
            for (int r = 0; r < 4; ++r) {
                int gr = rowBase + wm + im * 16 + quad * 4 + r;
                int gc = colBase + wn + in * 16 + l15;
                float v = acc[im][in][r] + bias[gc];
                fout[(size_t)gr * N + gc] = v + res[(size_t)gr * N + gc];
            }
        }
    }
}

// ---------------- 256^2 8-phase GEMM (T3+T4 counted-vmcnt + T5) ----------------
// BM=BN=256, BK=64, 8 waves (2M x 4N), 512 thr, LDS 128 KiB.
// v2: (a) sched_barrier(0) pins each phase's {ds/stage | wait | MFMA} sections
//     (rule #18: hipcc migrates reg-only MFMAs across asm waitcnt otherwise);
//     (b) deeper ledger -> 3 half-tiles in flight, vmcnt(6) at ph4/ph8.
// Ledger (stage -> slot), fixed-point verified:
//   ph1 A1(t+1)->As[1][1] | ph3 B0(t+2)->Bs[0][0] | ph4 B1(t+2)->Bs[0][1],
//   A0(t+2)->As[0][0] | ph5 A1(t+2)->As[0][1] | ph7 B0(t+3)->Bs[1][0] |
//   ph8 B1(t+3)->Bs[1][1], A0(t+3)->As[1][0]
// At ph4's vmcnt(6): drains exactly {B(t+1),A(t+1)} (read ph5-ph7).
// At ph8's vmcnt(6): drains exactly {B(t+2),A(t+2)} (read ph1'-ph3').
// Survivors after ph8 = {B0,B1,A0}(t+3) = 6 loads = prologue invariant.
// Slot-free proof: a slot's last ds_read completes at that phase's mid
// lgkmcnt(0) (per wave) before that wave's END barrier; stages sit in the
// NEXT phase's front section (post-END) -> no write-before-read race.
// MODE 0: QKV scatter (Q *0.125, K, V direct-transposed).  MODE 2: GELU->bf16.
template<int MODE>
__global__ __launch_bounds__(512, 2) void gemm256(
    const u16* __restrict__ A, const u16* __restrict__ BT,
    int M, int N, int K,
    const float* __restrict__ bias,
    u16* __restrict__ o0, u16* __restrict__ o1)
{
    __shared__ __attribute__((aligned(16))) u16 As[2][2][128 * 64];
    __shared__ __attribute__((aligned(16))) u16 Bs[2][2][128 * 64];
    int tid = threadIdx.x;
    int lane = tid & 63, w = tid >> 6;
    int wrow = w >> 2, wcol = w & 3;
    int l15 = lane & 15, quad = lane >> 4;
    int rowBase = blockIdx.y * 256, colBase = blockIdx.x * 256;
    int nrb = (wcol & 1) * 64;

    int swz[2] = { (quad ^ (l15 & 7)) * 8, ((4 + quad) ^ (l15 & 7)) * 8 };

    // staging precompute (32-bit offsets; max ~8.4M elements)
    int cid0 = tid, cid1 = 512 + tid;
    int r0 = cid0 >> 3, r1 = cid1 >> 3;
    unsigned cs0 = (unsigned)(((cid0 & 7) ^ (r0 & 7)) * 8);
    unsigned cs1 = (unsigned)(((cid1 & 7) ^ (r1 & 7)) * 8);
    unsigned aoff0 = (unsigned)((rowBase + r0) * K) + cs0;
    unsigned aoff1 = (unsigned)((rowBase + r1) * K) + cs1;
    unsigned boff0 = (unsigned)((colBase + r0) * K) + cs0;
    unsigned boff1 = (unsigned)((colBase + r1) * K) + cs1;
    unsigned ldo0 = (unsigned)(cid0 * 8), ldo1 = (unsigned)(cid1 * 8);
    unsigned hK = (unsigned)(128 * K);

    floatx4 acc[8][4] = {};
    short8 af[4][2], bfL[2][2], bfH[2][2];

    int KT = K >> 6;

#define STG_A(db, tt, h) do { unsigned tb_ = (unsigned)(tt) * 64u + (h) * hK;      \
    gld_lds16(A + aoff0 + tb_, &As[db][h][0] + ldo0);                              \
    gld_lds16(A + aoff1 + tb_, &As[db][h][0] + ldo1); } while (0)
#define STG_B(db, tt, h) do { unsigned tb_ = (unsigned)(tt) * 64u + (h) * hK;      \
    gld_lds16(BT + boff0 + tb_, &Bs[db][h][0] + ldo0);                             \
    gld_lds16(BT + boff1 + tb_, &Bs[db][h][0] + ldo1); } while (0)
#define LDS_A(buf, MFB) do { const u16* ap_ = &As[buf][wrow][0];                   \
    _Pragma("unroll") for (int m_ = 0; m_ < 4; ++m_) {                             \
      af[m_][0] = *(const short8*)(ap_ + (((MFB) + m_) * 16 + l15) * 64 + swz[0]); \
      af[m_][1] = *(const short8*)(ap_ + (((MFB) + m_) * 16 + l15) * 64 + swz[1]); } } while (0)
#define LDS_B(buf, NFP, dst) do { const u16* bp_ = &Bs[buf][wcol >> 1][0];         \
    _Pragma("unroll") for (int n_ = 0; n_ < 2; ++n_) {                             \
      dst[n_][0] = *(const short8*)(bp_ + (nrb + ((NFP) * 2 + n_) * 16 + l15) * 64 + swz[0]); \
      dst[n_][1] = *(const short8*)(bp_ + (nrb + ((NFP) * 2 + n_) * 16 + l15) * 64 + swz[1]); } } while (0)
#define MFMA_Q(MFB, NFP, bsrc) do { __builtin_amdgcn_s_setprio(1);                 \
    _Pragma("unroll") for (int m_ = 0; m_ < 4; ++m_)                               \
    _Pragma("unroll") for (int n_ = 0; n_ < 2; ++n_) {                             \
      acc[(MFB) + m_][(NFP) * 2 + n_] = __builtin_amdgcn_mfma_f32_16x16x32_bf16(af[m_][0], bsrc[n_][0], acc[(MFB) + m_][(NFP) * 2 + n_], 0, 0, 0); \
      acc[(MFB) + m_][(NFP) * 2 + n_] = __builtin_amdgcn_mfma_f32_16x16x32_bf16(af[m_][1], bsrc[n_][1], acc[(MFB) + m_][(NFP) * 2 + n_], 0, 0, 0); } \
    __builtin_amdgcn_s_setprio(0); } while (0)
#define PH_MID() do { __builtin_amdgcn_sched_barrier(0);                           \
    __builtin_amdgcn_s_barrier();                                                  \
    asm volatile("s_waitcnt lgkmcnt(0)" ::: "memory");                             \
    __builtin_amdgcn_sched_barrier(0); } while (0)
#define PH_END() do { __builtin_amdgcn_sched_barrier(0);                           \
    __builtin_amdgcn_s_barrier(); } while (0)

    // prologue: tile0 (4 halves) + B(1) (2) + A0(1); vmcnt(6) leaves the
    // {B0(1),B1(1),A0(1)} survivor set = steady-state invariant for t=0.
    STG_A(0, 0, 0); STG_A(0, 0, 1);
    STG_B(0, 0, 0); STG_B(0, 0, 1);
    STG_B(1, 1, 0); STG_B(1, 1, 1);
    STG_A(1, 1, 0);
    asm volatile("s_waitcnt vmcnt(6)" ::: "memory");
    __builtin_amdgcn_s_barrier();

    for (int t = 0; t < KT; t += 2) {
        int t2 = (t + 2 < KT) ? t + 2 : KT - 1;
        int t3 = (t + 3 < KT) ? t + 3 : KT - 1;

        // ph1: tile t (buf0) Q(M0-3,N0-1); stage A1(t+1)
        LDS_A(0, 0); LDS_B(0, 0, bfL);
        STG_A(1, t + 1, 1);
        asm volatile("s_waitcnt lgkmcnt(8)" ::: "memory");
        PH_MID(); MFMA_Q(0, 0, bfL); PH_END();

        // ph2: Q(M0-3,N2-3)
        LDS_B(0, 1, bfH);
        PH_MID(); MFMA_Q(0, 1, bfH); PH_END();

        // ph3: Q(M4-7,N2-3); stage B0(t+2)
        LDS_A(0, 4);
        STG_B(0, t2, 0);
        PH_MID(); MFMA_Q(4, 1, bfH); PH_END();

        // ph4: Q(M4-7,N0-1); stage B1(t+2)+A0(t+2); drain {B(t+1),A(t+1)}
        STG_B(0, t2, 1);
        STG_A(0, t2, 0);
        asm volatile("s_waitcnt vmcnt(6)" ::: "memory");
        PH_MID(); MFMA_Q(4, 0, bfL); PH_END();

        // ph5: tile t+1 (buf1) Q(M0-3,N0-1); stage A1(t+2)
        LDS_A(1, 0); LDS_B(1, 0, bfL);
        STG_A(0, t2, 1);
        asm volatile("s_waitcnt lgkmcnt(8)" ::: "memory");
        PH_MID(); MFMA_Q(0, 0, bfL); PH_END();

        // ph6: Q(M0-3,N2-3)
        LDS_B(1, 1, bfH);
        PH_MID(); MFMA_Q(0, 1, bfH); PH_END();

        // ph7: Q(M4-7,N2-3); stage B0(t+3)
        LDS_A(1, 4);
        STG_B(1, t3, 0);
        PH_MID(); MFMA_Q(4, 1, bfH); PH_END();

        // ph8: Q(M4-7,N0-1); stage B1(t+3)+A0(t+3); drain {B(t+2),A(t+2)}
        STG_B(1, t3, 1);
        STG_A(1, t3, 0);
        asm volatile("s_waitcnt vmcnt(6)" ::: "memory");
        PH_MID(); MFMA_Q(4, 0, bfL); PH_END();
    }
    asm volatile("s_waitcnt vmcnt(0)" ::: "memory");

#undef STG_A
#undef STG_B
#undef LDS_A
#undef LDS_B
#undef MFMA_Q
#undef PH_MID
#undef PH_END

    // epilogue
    int wr0 = rowBase + wrow * 128 + quad * 4;
    int wc0 = colBase + wcol * 64 + l15;
    if (MODE == 0) {
        int t = colBase >> 10;                    // uniform per block (q/k/v)
        int cb1023 = (colBase & 1023) + wcol * 64;
        if (t == 2) {
            // V: write directly transposed [BH,64,S]; r=0..3 are consecutive s
            #pragma unroll
            for (int mf = 0; mf < 8; ++mf) {
                int gr0 = wr0 + mf * 16;
                int bb2 = gr0 >> 11, ss = gr0 & 2047;
                #pragma unroll
                for (int nf = 0; nf < 4; ++nf) {
                    int gc = wc0 + nf * 16;
                    int rr = cb1023 + nf * 16 + l15;
                    int hh = rr >> 6, hd = rr & 63;
                    float bv = bias[gc];
                    ushort4_t pk;
                    pk.x = f2bf_fast(acc[mf][nf][0] + bv);
                    pk.y = f2bf_fast(acc[mf][nf][1] + bv);
                    pk.z = f2bf_fast(acc[mf][nf][2] + bv);
                    pk.w = f2bf_fast(acc[mf][nf][3] + bv);
                    *(ushort4_t*)(o1 + ((size_t)(bb2 * NHEAD + hh) * HDIM + hd) * S_LEN + ss) = pk;
                }
            }
        } else {
            u16* qb = o0 + (size_t)t * 8388608;    // 8192*1024 elements per tensor
            float sc = (t == 0) ? 0.125f : 1.0f;   // fold softmax 1/sqrt(64) into Q
            #pragma unroll
            for (int mf = 0; mf < 8; ++mf) {
                #pragma unroll
                for (int nf = 0; nf < 4; ++nf) {
                    int gc = wc0 + nf * 16;
                    int rr = cb1023 + nf * 16 + l15;
                    int hh = rr >> 6, hd = rr & 63;
                    #pragma unroll
                    for (int r = 0; r < 4; ++r) {
                        int gr = wr0 + mf * 16 + r;
                        float v = (acc[mf][nf][r] + bias[gc]) * sc;
                        int bb2 = gr >> 11, ss = gr & 2047;
                        qb[(((size_t)(bb2 * NHEAD + hh) * S_LEN + ss) * HDIM) + hd] = f2bf_fast(v);
                    }
                }
            }
        }
    } else {
        // MODE 2: GELU -> bf16 row-major
        #pragma unroll
        for (int mf = 0; mf < 8; ++mf) {
            #pragma unroll
            for (int nf = 0; nf < 4; ++nf) {
                int gc = wc0 + nf * 16;
                float bv = bias[gc];
                #pragma unroll
                for (int r = 0; r < 4; ++r) {
                    int gr = wr0 + mf * 16 + r;
                    float v = acc[mf][nf][r] + bv;
                    float p = v * (1.59576912f + 0.07135481f * v * v);
                    float e = __expf(-p);
                    float gl = v * __builtin_amdgcn_rcpf(1.0f + e);
                    o0[(size_t)gr * N + gc] = f2bf_fast(gl);
                }
            }
        }
    }
}

// ---------------- flash attention (causal), bf16 in/out ----------------
// Fixed-max softmax (scale pre-folded into Q). Macro Q-tile = 128 rows/block;
// each wave owns TWO 16-row strips 64 apart, so every K/V ds_read_b128 feeds
// MFMAs for 32 q-rows. Blocks handle macros {p, 15-p} -> 34 K-iters each.
// Grid (bh=64, p=8): ID%8 = bh%8 -> all p-blocks of one head share one XCD L2.
__global__ __launch_bounds__(256) void flash_attn(
    const u16* __restrict__ Q, const u16* __restrict__ Kb,
    const u16* __restrict__ Vt, u16* __restrict__ O)
{
    __shared__ __attribute__((aligned(16))) u16 Ks[2][64 * 64];
    __shared__ __attribute__((aligned(16))) u16 Vs[2][64 * 64];
    __shared__ __attribute__((aligned(16))) u16 Pl[4][2][16][64];
    int tid = threadIdx.x;
    int lane = tid & 63, w = tid >> 6;
    int l15 = lane & 15, quad = lane >> 4;
    int bh = blockIdx.x;           // 0..63 (fastest-varying -> XCD = bh%8)
    int pp = blockIdx.y;           // 0..7
    int bb = bh >> 4, h = bh & 15;

    const u16* Kp0 = Kb + (size_t)bh * S_LEN * HDIM;
    const u16* Vp  = Vt + (size_t)bh * HDIM * S_LEN;

    int rstage = lane >> 3;                       // 0..7
    int cstage = ((lane & 7) ^ rstage) * 8;       // swizzled source chunk (u16 units)
    int vrow0  = w * 8 + rstage;                  // staging row within 32-row half

    int ms[2] = {pp, 15 - pp};
    int pb = 0;

    // prologue: stage K/V tile kt=0 into parity 0
    #pragma unroll
    for (int i = 0; i < 2; ++i) {
        int row = i * 32 + vrow0;
        gld_lds16(Kp0 + row * HDIM + cstage, &Ks[0][0] + i * 2048 + w * 512);
        gld_lds16(Vp + (size_t)row * S_LEN + cstage, &Vs[0][0] + i * 2048 + w * 512);
    }

    #pragma unroll 1
    for (int sel = 0; sel < 2; ++sel) {
        int m = ms[sel];
        int q0 = m * 128;

        // Q fragments for both strips (strip1 = +64 rows)
        const u16* Qp = Q + ((size_t)bh * S_LEN + q0 + w * 16) * HDIM;
        short8 aq0[2], aq1[2];
        #pragma unroll
        for (int ks = 0; ks < 2; ++ks) {
            aq0[ks] = *(const short8*)(Qp + l15 * HDIM + ks * 32 + quad * 8);
            aq1[ks] = *(const short8*)(Qp + 64 * HDIM + l15 * HDIM + ks * 32 + quad * 8);
        }

        floatx4 acc_o0[4] = {}, acc_o1[4] = {};
        float rs0[4] = {0.f, 0.f, 0.f, 0.f};
        float rs1[4] = {0.f, 0.f, 0.f, 0.f};

        int KT = 2 * m + 2;   // K-tiles this macro (strip1 needs kt <= 2m+1)

        auto softmax_store = [&](floatx4 (&sa)[4], float (&rs)[4], int st, bool diag) {
            #pragma unroll
            for (int nt = 0; nt < 4; ++nt) {
                int wc = nt * 16 + l15;
                int wchunk = wc >> 3, woff = wc & 7;
                #pragma unroll
                for (int r = 0; r < 4; ++r) {
                    float sv = sa[nt][r];           // scale already folded into Q
                    if (diag) {
                        int qr = w * 16 + quad * 4 + r;
                        if (wc > qr) sv = -1e30f;
                    }
                    float pv = __expf(sv);          // fixed-max softmax; exp(-1e30)=0
                    rs[r] += pv;
                    int row = quad * 4 + r;
                    Pl[w][st][row][((wchunk ^ (row & 7)) << 3) + woff] = f2bf_fast(pv);
                }
            }
        };

        #pragma unroll 1
        for (int kt = 0; kt < KT; ++kt) {
            __syncthreads();   // tile kt (parity pb) resident; drain covered by prior phase
            int cur = pb;

            // prefetch next tile: kt+1, or next macro's kt=0
            int nk = (kt + 1 < KT) ? (kt + 1) : ((sel < 1) ? 0 : -1);
            if (nk >= 0) {
                pb ^= 1;
                const u16* Kg = Kp0 + (size_t)nk * 64 * HDIM;
                const u16* Vg = Vp + nk * 64;
                u16* kb_ = &Ks[pb][0];
                u16* vb_ = &Vs[pb][0];
                #pragma unroll
                for (int i = 0; i < 2; ++i) {
                    int row = i * 32 + vrow0;
                    gld_lds16(Kg + row * HDIM + cstage, kb_ + i * 2048 + w * 512);
                    gld_lds16(Vg + (size_t)row * S_LEN + cstage, vb_ + i * 2048 + w * 512);
                }
            }

            const u16* kcur = &Ks[cur][0];
            const u16* vcur = &Vs[cur][0];

            bool a0 = (kt < KT - 1);      // strip0 active (kt <= 2m)

            // QK^T: shared K-frag reads feed both strips
            floatx4 s0a[4] = {}, s1a[4] = {};
            __builtin_amdgcn_s_setprio(1);
            #pragma unroll
            for (int nt = 0; nt < 4; ++nt) {
                #pragma unroll
                for (int ks = 0; ks < 2; ++ks) {
                    int sw = ((ks * 4 + quad) ^ (l15 & 7)) * 8;
                    short8 bk = *(const short8*)(kcur + (nt * 16 + l15) * 64 + sw);
                    s0a[nt] = __builtin_amdgcn_mfma_f32_16x16x32_bf16(aq0[ks], bk, s0a[nt], 0, 0, 0);
                    s1a[nt] = __builtin_amdgcn_mfma_f32_16x16x32_bf16(aq1[ks], bk, s1a[nt], 0, 0, 0);
                }
            }
            __builtin_amdgcn_s_setprio(0);

            if (a0) softmax_store(s0a, rs0, 0, kt == KT - 2);
            softmax_store(s1a, rs1, 1, kt == KT - 1);

            // per-wave LDS round-trip: same-wave DS ordering, no barrier needed
            short8 pf0[2] = {}, pf1[2];
            if (a0) {
                #pragma unroll
                for (int ks = 0; ks < 2; ++ks) {
                    int pc = ((ks * 4 + quad) ^ (l15 & 7)) * 8;
                    pf0[ks] = *(const short8*)(&Pl[w][0][l15][pc]);
                }
            }
            #pragma unroll
            for (int ks = 0; ks < 2; ++ks) {
                int pc = ((ks * 4 + quad) ^ (l15 & 7)) * 8;
                pf1[ks] = *(const short8*)(&Pl[w][1][l15][pc]);
            }

            // PV: shared V-frag reads feed both strips (pf0 zeroed when inactive)
            __builtin_amdgcn_s_setprio(1);
            #pragma unroll
            for (int nt = 0; nt < 4; ++nt) {
                #pragma unroll
                for (int ks = 0; ks < 2; ++ks) {
                    int sw = ((ks * 4 + quad) ^ (l15 & 7)) * 8;
                    short8 bv = *(const short8*)(vcur + (nt * 16 + l15) * 64 + sw);
                    acc_o0[nt] = __builtin_amdgcn_mfma_f32_16x16x32_bf16(pf0[ks], bv, acc_o0[nt], 0, 0, 0);
                    acc_o1[nt] = __builtin_amdgcn_mfma_f32_16x16x32_bf16(pf1[ks], bv, acc_o1[nt], 0, 0, 0);
                }
            }
            __builtin_amdgcn_s_setprio(0);
        }

        float inv0[4], inv1[4];
        #pragma unroll
        for (int r = 0; r < 4; ++r) {
            float sm0 = rs0[r], sm1 = rs1[r];
            #pragma unroll
            for (int off = 1; off < 16; off <<= 1) {
                sm0 += __shfl_xor(sm0, off, 64);
                sm1 += __shfl_xor(sm1, off, 64);
            }
            inv0[r] = 1.0f / sm0;
            inv1[r] = 1.0f / sm1;
        }

        #pragma unroll
        for (int nt = 0; nt < 4; ++nt) {
            #pragma unroll
            for (int r = 0; r < 4; ++r) {
                int qr = q0 + w * 16 + quad * 4 + r;
                int hd = nt * 16 + l15;
                O[((size_t)bb * S_LEN + qr) * DMODEL + h * HDIM + hd] = f2bf(acc_o0[nt][r] * inv0[r]);
                O[((size_t)bb * S_LEN + qr + 64) * DMODEL + h * HDIM + hd] = f2bf(acc_o1[nt][r] * inv1[r]);
            }
        }
    }
}

extern "C" void kernel_launch(void* const* d_in, const int* in_sizes, int n_in,
                              void* d_out, int out_size, void* d_ws, size_t ws_size,
                              hipStream_t stream)
{
    const float* x    = (const float*)d_in[0];
    const float* ln1g = (const float*)d_in[2];
    const float* ln1b = (const float*)d_in[3];
    const float* wqkv = (const float*)d_in[4];
    const float* bqkv = (const float*)d_in[5];
    const float* wao  = (const float*)d_in[6];
    const float* bao  = (const float*)d_in[7];
    const float* ln2g = (const float*)d_in[8];
    const float* ln2b = (const float*)d_in[9];
    const float* wfc  = (const float*)d_in[10];
    const float* bfc  = (const float*)d_in[11];
    const float* wout = (const float*)d_in[12];
    const float* bout = (const float*)d_in[13];
    float* out = (float*)d_out;

    char* ws = (char*)d_ws;
    u16* wqkvT = (u16*)(ws + 0);          //  6.3 MB
    u16* waoT  = (u16*)(ws + 6291456);    //  2.1 MB
    u16* wfcT  = (u16*)(ws + 8388608);    //  8.4 MB
    u16* woutT = (u16*)(ws + 16777216);   //  8.4 MB
    u16* hb    = (u16*)(ws + 25165824);   // 16.8 MB: LN1 out; attn out; later h2
    u16* QKVb  = (u16*)(ws + 41943040);   // 50.3 MB: Q|K each 8.4M elements (V slot unused)
    u16* Vtb   = (u16*)(ws + 92274688);   // 16.8 MB: V^T (written directly by gemm256<0>)
    u16* Gb    = (u16*)(ws + 41943040);   // 67.1 MB: GELU out (QKV+Vt dead by then)

    u16* Qb   = QKVb;
    u16* Kbuf = QKVb + 8388608;

    transpose_cast<<<dim3(3072/32, 1024/32), dim3(32, 8), 0, stream>>>(wqkv, wqkvT, 1024, 3072);
    transpose_cast<<<dim3(1024/32, 1024/32), dim3(32, 8), 0, stream>>>(wao,  waoT,  1024, 1024);
    transpose_cast<<<dim3(4096/32, 1024/32), dim3(32, 8), 0, stream>>>(wfc,  wfcT,  1024, 4096);
    transpose_cast<<<dim3(1024/32, 4096/32), dim3(32, 8), 0, stream>>>(wout, woutT, 4096, 1024);

    ln_kernel<<<8192, 256, 0, stream>>>(x, ln1g, ln1b, hb);

    gemm256<0><<<dim3(3072/256, 8192/256), 512, 0, stream>>>(
        hb, wqkvT, 8192, 3072, 1024, bqkv, QKVb, Vtb);

    flash_attn<<<dim3(64, 8), 256, 0, stream>>>(Qb, Kbuf, Vtb, hb);

    gemm_bt<1><<<dim3(1024/128, 8192/128), 256, 0, stream>>>(
        hb, waoT, 8192, 1024, 1024, bao, x, out, nullptr, nullptr, nullptr);

    ln_kernel<<<8192, 256, 0, stream>>>(out, ln2g, ln2b, hb);

    gemm256<2><<<dim3(4096/256, 8192/256), 512, 0, stream>>>(
        hb, wfcT, 8192, 4096, 1024, bfc, Gb, nullptr);

    gemm_bt<3><<<dim3(1024/128, 8192/128), 256, 0, stream>>>(
        Gb, woutT, 8192, 1024, 4096, bout, out, out, nullptr, nullptr, nullptr);
}

// Round 8
// 493.736 us; speedup vs baseline: 1.0350x; 1.0313x over previous
//
#include <hip/hip_runtime.h>

typedef unsigned short u16;
typedef __attribute__((ext_vector_type(8))) short short8;
typedef __attribute__((ext_vector_type(4))) float floatx4;
typedef __attribute__((ext_vector_type(4))) unsigned short ushort4_t;

#define S_LEN 2048
#define DMODEL 1024
#define NHEAD 16
#define HDIM 64

__device__ __forceinline__ u16 f2bf(float f) {
    union { float f; unsigned u; } v; v.f = f;
    unsigned u = v.u;
    unsigned r = (u + 0x7fffu + ((u >> 16) & 1u)) >> 16;
    return (u16)r;
}

// round-half-up bf16 pack (2 VALU ops) — for GEMM-feeding intermediates
__device__ __forceinline__ u16 f2bf_fast(float f) {
    union { float f; unsigned u; } v; v.f = f;
    return (u16)((v.u + 0x8000u) >> 16);
}

__device__ __forceinline__ void gld_lds16(const u16* g, u16* l) {
    __builtin_amdgcn_global_load_lds((const __attribute__((address_space(1))) void*)g,
                                     (__attribute__((address_space(3))) void*)l,
                                     16, 0, 0);
}

// ---------------- LayerNorm -> bf16 ----------------
__global__ __launch_bounds__(256) void ln_kernel(
    const float* __restrict__ x, const float* __restrict__ g,
    const float* __restrict__ b, u16* __restrict__ out)
{
    int row = blockIdx.x;
    int tid = threadIdx.x;
    const float4* xr = (const float4*)(x + (size_t)row * DMODEL);
    float4 v = xr[tid];
    float s  = v.x + v.y + v.z + v.w;
    float s2 = v.x * v.x + v.y * v.y + v.z * v.z + v.w * v.w;
    #pragma unroll
    for (int off = 1; off < 64; off <<= 1) {
        s  += __shfl_xor(s, off, 64);
        s2 += __shfl_xor(s2, off, 64);
    }
    __shared__ float red[2][4];
    int w = tid >> 6, lane = tid & 63;
    if (lane == 0) { red[0][w] = s; red[1][w] = s2; }
    __syncthreads();
    s  = red[0][0] + red[0][1] + red[0][2] + red[0][3];
    s2 = red[1][0] + red[1][1] + red[1][2] + red[1][3];
    float mu  = s * (1.0f / DMODEL);
    float var = s2 * (1.0f / DMODEL) - mu * mu;
    float inv = rsqrtf(var + 1e-5f);
    const float4* gr = (const float4*)g;
    const float4* br = (const float4*)b;
    float4 gv = gr[tid], bv = br[tid];
    u16* o = out + (size_t)row * DMODEL + tid * 4;
    o[0] = f2bf((v.x - mu) * inv * gv.x + bv.x);
    o[1] = f2bf((v.y - mu) * inv * gv.y + bv.y);
    o[2] = f2bf((v.z - mu) * inv * gv.z + bv.z);
    o[3] = f2bf((v.w - mu) * inv * gv.w + bv.w);
}

// ---------------- weight transpose + cast: wt[n][k] = bf16(w[k][n]) ----------------
__global__ __launch_bounds__(256) void transpose_cast(
    const float* __restrict__ w, u16* __restrict__ wt, int K, int N)
{
    __shared__ float t[32][33];
    int n0 = blockIdx.x * 32, k0 = blockIdx.y * 32;
    int x = threadIdx.x, y = threadIdx.y;
    #pragma unroll
    for (int j = y; j < 32; j += 8)
        t[j][x] = w[(size_t)(k0 + j) * N + n0 + x];
    __syncthreads();
    #pragma unroll
    for (int j = y; j < 32; j += 8)
        wt[(size_t)(n0 + j) * K + k0 + x] = f2bf(t[x][j]);
}

// ---------------- legacy 128^2 GEMM (QKV / AO / FC2) ----------------
// Single-barrier double-buffered K-loop; staging pointers incremented.
// MODE 0: QKV -> Q (*0.125 folded) and K in [BH,S,64] at o0; V DIRECTLY
//         transposed [BH,64,S] into o1 (4 consecutive s packed per store).
// MODE 1/3: fout = C + bias + res (fp32)
// MODE 2: o0 = bf16(gelu(C + bias))
template<int MODE>
__global__ __launch_bounds__(256) void gemm_bt(
    const u16* __restrict__ A, const u16* __restrict__ BT,
    int M, int N, int K,
    const float* __restrict__ bias, const float* __restrict__ res,
    float* __restrict__ fout,
    u16* __restrict__ o0, u16* __restrict__ o1, u16* __restrict__ o2)
{
    __shared__ __attribute__((aligned(16))) u16 As[2][128 * 64];
    __shared__ __attribute__((aligned(16))) u16 Bs[2][128 * 64];
    int tid = threadIdx.x;
    int lane = tid & 63, w = tid >> 6;
    int wm = (w >> 1) * 64, wn = (w & 1) * 64;
    int l15 = lane & 15, quad = lane >> 4;
    int rowBase = blockIdx.y * 128, colBase = blockIdx.x * 128;

    floatx4 acc[4][4] = {};

    const u16* pa[4];
    const u16* pbt[4];
    int scb[4];
    #pragma unroll
    for (int i = 0; i < 4; ++i) {
        int c  = i * 256 + tid;
        int r  = c >> 3;
        int cs = ((c & 7) ^ (r & 7)) * 8;            // swizzled source chunk
        pa[i]  = A  + (size_t)(rowBase + r) * K + cs;
        pbt[i] = BT + (size_t)(colBase + r) * K + cs;
        scb[i] = (i * 256 + (tid & 0xC0)) * 8;       // wave-uniform LDS base
    }

    int KT = K >> 6;

    #pragma unroll
    for (int i = 0; i < 4; ++i) {
        gld_lds16(pa[i],  &As[0][0] + scb[i]);
        gld_lds16(pbt[i], &Bs[0][0] + scb[i]);
    }

    for (int kt = 0; kt < KT; ++kt) {
        __syncthreads();

        if (kt + 1 < KT) {
            u16* abuf = &As[(kt + 1) & 1][0];
            u16* bbuf = &Bs[(kt + 1) & 1][0];
            #pragma unroll
            for (int i = 0; i < 4; ++i) {
                pa[i]  += 64;
                pbt[i] += 64;
                gld_lds16(pa[i],  abuf + scb[i]);
                gld_lds16(pbt[i], bbuf + scb[i]);
            }
        }

        const u16* as = &As[kt & 1][0];
        const u16* bs = &Bs[kt & 1][0];
        #pragma unroll
        for (int ks = 0; ks < 2; ++ks) {
            int sw = (((ks * 4 + quad) ^ (l15 & 7))) * 8;
            short8 af[4], bf[4];
            #pragma unroll
            for (int im = 0; im < 4; ++im)
                af[im] = *(const short8*)(as + (wm + im * 16 + l15) * 64 + sw);
            #pragma unroll
            for (int in = 0; in < 4; ++in)
                bf[in] = *(const short8*)(bs + (wn + in * 16 + l15) * 64 + sw);
            #pragma unroll
            for (int im = 0; im < 4; ++im)
                #pragma unroll
                for (int in = 0; in < 4; ++in)
                    acc[im][in] = __builtin_amdgcn_mfma_f32_16x16x32_bf16(af[im], bf[in], acc[im][in], 0, 0, 0);
        }
    }

    // epilogue
    if (MODE == 0) {
        int t = colBase >> 10;                 // uniform per block (q/k/v)
        int cb1023 = colBase & 1023;
        if (t == 2) {
            // V: write directly transposed [BH,64,S]; r=0..3 are consecutive s
            #pragma unroll
            for (int im = 0; im < 4; ++im) {
                int gr0 = rowBase + wm + im * 16 + quad * 4;
                int bb2 = gr0 >> 11, ss = gr0 & 2047;
                #pragma unroll
                for (int in = 0; in < 4; ++in) {
                    int gc = colBase + wn + in * 16 + l15;
                    int rr = cb1023 + wn + in * 16 + l15;
                    int hh = rr >> 6, hd = rr & 63;
                    float bv = bias[gc];
                    ushort4_t pk;
                    pk.x = f2bf_fast(acc[im][in][0] + bv);
                    pk.y = f2bf_fast(acc[im][in][1] + bv);
                    pk.z = f2bf_fast(acc[im][in][2] + bv);
                    pk.w = f2bf_fast(acc[im][in][3] + bv);
                    *(ushort4_t*)(o1 + ((size_t)(bb2 * NHEAD + hh) * HDIM + hd) * S_LEN + ss) = pk;
                }
            }
        } else {
            u16* qb = o0 + (size_t)t * 8388608;    // 8192*1024 elements per tensor
            float sc = (t == 0) ? 0.125f : 1.0f;   // fold softmax 1/sqrt(64) into Q
            #pragma unroll
            for (int im = 0; im < 4; ++im) {
                #pragma unroll
                for (int in = 0; in < 4; ++in) {
                    #pragma unroll
                    for (int r = 0; r < 4; ++r) {
                        int gr = rowBase + wm + im * 16 + quad * 4 + r;
                        int gc = colBase + wn + in * 16 + l15;
                        float v = (acc[im][in][r] + bias[gc]) * sc;
                        int rr = cb1023 + wn + in * 16 + l15;
                        int hh = rr >> 6, hd = rr & 63;
                        int bb2 = gr >> 11, ss = gr & 2047;
                        qb[(((size_t)(bb2 * NHEAD + hh) * S_LEN + ss) * HDIM) + hd] = f2bf_fast(v);
                    }
                }
            }
        }
    } else {
        #pragma unroll
        for (int im = 0; im < 4; ++im) {
            #pragma unroll
            for (int in = 0; in < 4; ++in) {
                #pragma unroll
                for (int r = 0; r < 4; ++r) {
                    int gr = rowBase + wm + im * 16 + quad * 4 + r;
                    int gc = colBase + wn + in * 16 + l15;
                    float v = acc[im][in][r] + bias[gc];
                    if (MODE == 2) {
                        float p = v * (1.59576912f + 0.07135481f * v * v);
                        float e = __expf(-p);
                        float gl = v * __builtin_amdgcn_rcpf(1.0f + e);
                        o0[(size_t)gr * N + gc] = f2bf_fast(gl);
                    } else {
                        fout[(size_t)gr * N + gc] = v + res[(size_t)gr * N + gc];
                    }
                }
            }
        }
    }
}

// ---------------- 256^2 8-phase GEMM (FC1 only: grid 16x32 = 2 full rounds) ----------------
// Verified passing in rounds 3/5 (88.6 us vs legacy 90.9 at this shape).
template<int MODE>
__global__ __launch_bounds__(512, 2) void gemm256(
    const u16* __restrict__ A, const u16* __restrict__ BT,
    int M, int N, int K,
    const float* __restrict__ bias,
    u16* __restrict__ o0, u16* __restrict__ o1)
{
    __shared__ __attribute__((aligned(16))) u16 As[2][2][128 * 64];
    __shared__ __attribute__((aligned(16))) u16 Bs[2][2][128 * 64];
    int tid = threadIdx.x;
    int lane = tid & 63, w = tid >> 6;
    int wrow = w >> 2, wcol = w & 3;
    int l15 = lane & 15, quad = lane >> 4;
    int rowBase = blockIdx.y * 256, colBase = blockIdx.x * 256;
    int nrb = (wcol & 1) * 64;

    int swz[2] = { (quad ^ (l15 & 7)) * 8, ((4 + quad) ^ (l15 & 7)) * 8 };

    int cid0 = tid, cid1 = 512 + tid;
    int r0 = cid0 >> 3, r1 = cid1 >> 3;
    unsigned cs0 = (unsigned)(((cid0 & 7) ^ (r0 & 7)) * 8);
    unsigned cs1 = (unsigned)(((cid1 & 7) ^ (r1 & 7)) * 8);
    unsigned aoff0 = (unsigned)((rowBase + r0) * K) + cs0;
    unsigned aoff1 = (unsigned)((rowBase + r1) * K) + cs1;
    unsigned boff0 = (unsigned)((colBase + r0) * K) + cs0;
    unsigned boff1 = (unsigned)((colBase + r1) * K) + cs1;
    unsigned ldo0 = (unsigned)(cid0 * 8), ldo1 = (unsigned)(cid1 * 8);
    unsigned hK = (unsigned)(128 * K);

    floatx4 acc[8][4] = {};
    short8 af[4][2], bfL[2][2], bfH[2][2];

    int KT = K >> 6;

#define STG_A(db, tt, h) do { unsigned tb_ = (unsigned)(tt) * 64u + (h) * hK;      \
    gld_lds16(A + aoff0 + tb_, &As[db][h][0] + ldo0);                              \
    gld_lds16(A + aoff1 + tb_, &As[db][h][0] + ldo1); } while (0)
#define STG_B(db, tt, h) do { unsigned tb_ = (unsigned)(tt) * 64u + (h) * hK;      \
    gld_lds16(BT + boff0 + tb_, &Bs[db][h][0] + ldo0);                             \
    gld_lds16(BT + boff1 + tb_, &Bs[db][h][0] + ldo1); } while (0)
#define LDS_A(buf, MFB) do { const u16* ap_ = &As[buf][wrow][0];                   \
    _Pragma("unroll") for (int m_ = 0; m_ < 4; ++m_) {                             \
      af[m_][0] = *(const short8*)(ap_ + (((MFB) + m_) * 16 + l15) * 64 + swz[0]); \
      af[m_][1] = *(const short8*)(ap_ + (((MFB) + m_) * 16 + l15) * 64 + swz[1]); } } while (0)
#define LDS_B(buf, NFP, dst) do { const u16* bp_ = &Bs[buf][wcol >> 1][0];         \
    _Pragma("unroll") for (int n_ = 0; n_ < 2; ++n_) {                             \
      dst[n_][0] = *(const short8*)(bp_ + (nrb + ((NFP) * 2 + n_) * 16 + l15) * 64 + swz[0]); \
      dst[n_][1] = *(const short8*)(bp_ + (nrb + ((NFP) * 2 + n_) * 16 + l15) * 64 + swz[1]); } } while (0)
#define MFMA_Q(MFB, NFP, bsrc) do { __builtin_amdgcn_s_setprio(1);                 \
    _Pragma("unroll") for (int m_ = 0; m_ < 4; ++m_)                               \
    _Pragma("unroll") for (int n_ = 0; n_ < 2; ++n_) {                             \
      acc[(MFB) + m_][(NFP) * 2 + n_] = __builtin_amdgcn_mfma_f32_16x16x32_bf16(af[m_][0], bsrc[n_][0], acc[(MFB) + m_][(NFP) * 2 + n_], 0, 0, 0); \
      acc[(MFB) + m_][(NFP) * 2 + n_] = __builtin_amdgcn_mfma_f32_16x16x32_bf16(af[m_][1], bsrc[n_][1], acc[(MFB) + m_][(NFP) * 2 + n_], 0, 0, 0); } \
    __builtin_amdgcn_s_setprio(0); } while (0)
#define PH_MID() do { __builtin_amdgcn_sched_barrier(0);                           \
    __builtin_amdgcn_s_barrier();                                                  \
    asm volatile("s_waitcnt lgkmcnt(0)" ::: "memory");                             \
    __builtin_amdgcn_sched_barrier(0); } while (0)
#define PH_END() do { __builtin_amdgcn_sched_barrier(0);                           \
    __builtin_amdgcn_s_barrier(); } while (0)

    STG_A(0, 0, 0); STG_A(0, 0, 1);
    STG_B(0, 0, 0); STG_B(0, 0, 1);
    STG_B(1, 1, 0); STG_B(1, 1, 1);
    STG_A(1, 1, 0);
    asm volatile("s_waitcnt vmcnt(6)" ::: "memory");
    __builtin_amdgcn_s_barrier();

    for (int t = 0; t < KT; t += 2) {
        int t2 = (t + 2 < KT) ? t + 2 : KT - 1;
        int t3 = (t + 3 < KT) ? t + 3 : KT - 1;

        LDS_A(0, 0); LDS_B(0, 0, bfL);
        STG_A(1, t + 1, 1);
        asm volatile("s_waitcnt lgkmcnt(8)" ::: "memory");
        PH_MID(); MFMA_Q(0, 0, bfL); PH_END();

        LDS_B(0, 1, bfH);
        PH_MID(); MFMA_Q(0, 1, bfH); PH_END();

        LDS_A(0, 4);
        STG_B(0, t2, 0);
        PH_MID(); MFMA_Q(4, 1, bfH); PH_END();

        STG_B(0, t2, 1);
        STG_A(0, t2, 0);
        asm volatile("s_waitcnt vmcnt(6)" ::: "memory");
        PH_MID(); MFMA_Q(4, 0, bfL); PH_END();

        LDS_A(1, 0); LDS_B(1, 0, bfL);
        STG_A(0, t2, 1);
        asm volatile("s_waitcnt lgkmcnt(8)" ::: "memory");
        PH_MID(); MFMA_Q(0, 0, bfL); PH_END();

        LDS_B(1, 1, bfH);
        PH_MID(); MFMA_Q(0, 1, bfH); PH_END();

        LDS_A(1, 4);
        STG_B(1, t3, 0);
        PH_MID(); MFMA_Q(4, 1, bfH); PH_END();

        STG_B(1, t3, 1);
        STG_A(1, t3, 0);
        asm volatile("s_waitcnt vmcnt(6)" ::: "memory");
        PH_MID(); MFMA_Q(4, 0, bfL); PH_END();
    }
    asm volatile("s_waitcnt vmcnt(0)" ::: "memory");

#undef STG_A
#undef STG_B
#undef LDS_A
#undef LDS_B
#undef MFMA_Q
#undef PH_MID
#undef PH_END

    int wr0 = rowBase + wrow * 128 + quad * 4;
    int wc0 = colBase + wcol * 64 + l15;
    // MODE 2: GELU -> bf16 row-major (FC1)
    #pragma unroll
    for (int mf = 0; mf < 8; ++mf) {
        #pragma unroll
        for (int nf = 0; nf < 4; ++nf) {
            int gc = wc0 + nf * 16;
            float bv = bias[gc];
            #pragma unroll
            for (int r = 0; r < 4; ++r) {
                int gr = wr0 + mf * 16 + r;
                float v = acc[mf][nf][r] + bv;
                float p = v * (1.59576912f + 0.07135481f * v * v);
                float e = __expf(-p);
                float gl = v * __builtin_amdgcn_rcpf(1.0f + e);
                o0[(size_t)gr * N + gc] = f2bf_fast(gl);
            }
        }
    }
}

// ---------------- flash attention (causal), bf16 in/out ----------------
// Fixed-max softmax (scale pre-folded into Q). Macro Q-tile = 128 rows/block;
// each wave owns TWO 16-row strips 64 apart, so every K/V ds_read_b128 feeds
// MFMAs for 32 q-rows. Blocks handle macros {p, 15-p} -> 34 K-iters each.
// Grid (bh=64, p=8): ID%8 = bh%8 -> all p-blocks of one head share one XCD L2.
__global__ __launch_bounds__(256) void flash_attn(
    const u16* __restrict__ Q, const u16* __restrict__ Kb,
    const u16* __restrict__ Vt, u16* __restrict__ O)
{
    __shared__ __attribute__((aligned(16))) u16 Ks[2][64 * 64];
    __shared__ __attribute__((aligned(16))) u16 Vs[2][64 * 64];
    __shared__ __attribute__((aligned(16))) u16 Pl[4][2][16][64];
    int tid = threadIdx.x;
    int lane = tid & 63, w = tid >> 6;
    int l15 = lane & 15, quad = lane >> 4;
    int bh = blockIdx.x;           // 0..63 (fastest-varying -> XCD = bh%8)
    int pp = blockIdx.y;           // 0..7
    int bb = bh >> 4, h = bh & 15;

    const u16* Kp0 = Kb + (size_t)bh * S_LEN * HDIM;
    const u16* Vp  = Vt + (size_t)bh * HDIM * S_LEN;

    int rstage = lane >> 3;                       // 0..7
    int cstage = ((lane & 7) ^ rstage) * 8;       // swizzled source chunk (u16 units)
    int vrow0  = w * 8 + rstage;                  // staging row within 32-row half

    int ms[2] = {pp, 15 - pp};
    int pb = 0;

    // prologue: stage K/V tile kt=0 into parity 0
    #pragma unroll
    for (int i = 0; i < 2; ++i) {
        int row = i * 32 + vrow0;
        gld_lds16(Kp0 + row * HDIM + cstage, &Ks[0][0] + i * 2048 + w * 512);
        gld_lds16(Vp + (size_t)row * S_LEN + cstage, &Vs[0][0] + i * 2048 + w * 512);
    }

    #pragma unroll 1
    for (int sel = 0; sel < 2; ++sel) {
        int m = ms[sel];
        int q0 = m * 128;

        const u16* Qp = Q + ((size_t)bh * S_LEN + q0 + w * 16) * HDIM;
        short8 aq0[2], aq1[2];
        #pragma unroll
        for (int ks = 0; ks < 2; ++ks) {
            aq0[ks] = *(const short8*)(Qp + l15 * HDIM + ks * 32 + quad * 8);
            aq1[ks] = *(const short8*)(Qp + 64 * HDIM + l15 * HDIM + ks * 32 + quad * 8);
        }

        floatx4 acc_o0[4] = {}, acc_o1[4] = {};
        float rs0[4] = {0.f, 0.f, 0.f, 0.f};
        float rs1[4] = {0.f, 0.f, 0.f, 0.f};

        int KT = 2 * m + 2;   // K-tiles this macro (strip1 needs kt <= 2m+1)

        auto softmax_store = [&](floatx4 (&sa)[4], float (&rs)[4], int st, bool diag) {
            #pragma unroll
            for (int nt = 0; nt < 4; ++nt) {
                int wc = nt * 16 + l15;
                int wchunk = wc >> 3, woff = wc & 7;
                #pragma unroll
                for (int r = 0; r < 4; ++r) {
                    float sv = sa[nt][r];           // scale already folded into Q
                    if (diag) {
                        int qr = w * 16 + quad * 4 + r;
                        if (wc > qr) sv = -1e30f;
                    }
                    float pv = __expf(sv);          // fixed-max softmax; exp(-1e30)=0
                    rs[r] += pv;
                    int row = quad * 4 + r;
                    Pl[w][st][row][((wchunk ^ (row & 7)) << 3) + woff] = f2bf_fast(pv);
                }
            }
        };

        #pragma unroll 1
        for (int kt = 0; kt < KT; ++kt) {
            __syncthreads();   // tile kt (parity pb) resident; drain covered by prior phase
            int cur = pb;

            int nk = (kt + 1 < KT) ? (kt + 1) : ((sel < 1) ? 0 : -1);
            if (nk >= 0) {
                pb ^= 1;
                const u16* Kg = Kp0 + (size_t)nk * 64 * HDIM;
                const u16* Vg = Vp + nk * 64;
                u16* kb_ = &Ks[pb][0];
                u16* vb_ = &Vs[pb][0];
                #pragma unroll
                for (int i = 0; i < 2; ++i) {
                    int row = i * 32 + vrow0;
                    gld_lds16(Kg + row * HDIM + cstage, kb_ + i * 2048 + w * 512);
                    gld_lds16(Vg + (size_t)row * S_LEN + cstage, vb_ + i * 2048 + w * 512);
                }
            }

            const u16* kcur = &Ks[cur][0];
            const u16* vcur = &Vs[cur][0];

            bool a0 = (kt < KT - 1);      // strip0 active (kt <= 2m)

            floatx4 s0a[4] = {}, s1a[4] = {};
            __builtin_amdgcn_s_setprio(1);
            #pragma unroll
            for (int nt = 0; nt < 4; ++nt) {
                #pragma unroll
                for (int ks = 0; ks < 2; ++ks) {
                    int sw = ((ks * 4 + quad) ^ (l15 & 7)) * 8;
                    short8 bk = *(const short8*)(kcur + (nt * 16 + l15) * 64 + sw);
                    s0a[nt] = __builtin_amdgcn_mfma_f32_16x16x32_bf16(aq0[ks], bk, s0a[nt], 0, 0, 0);
                    s1a[nt] = __builtin_amdgcn_mfma_f32_16x16x32_bf16(aq1[ks], bk, s1a[nt], 0, 0, 0);
                }
            }
            __builtin_amdgcn_s_setprio(0);

            if (a0) softmax_store(s0a, rs0, 0, kt == KT - 2);
            softmax_store(s1a, rs1, 1, kt == KT - 1);

            short8 pf0[2] = {}, pf1[2];
            if (a0) {
                #pragma unroll
                for (int ks = 0; ks < 2; ++ks) {
                    int pc = ((ks * 4 + quad) ^ (l15 & 7)) * 8;
                    pf0[ks] = *(const short8*)(&Pl[w][0][l15][pc]);
                }
            }
            #pragma unroll
            for (int ks = 0; ks < 2; ++ks) {
                int pc = ((ks * 4 + quad) ^ (l15 & 7)) * 8;
                pf1[ks] = *(const short8*)(&Pl[w][1][l15][pc]);
            }

            __builtin_amdgcn_s_setprio(1);
            #pragma unroll
            for (int nt = 0; nt < 4; ++nt) {
                #pragma unroll
                for (int ks = 0; ks < 2; ++ks) {
                    int sw = ((ks * 4 + quad) ^ (l15 & 7)) * 8;
                    short8 bv = *(const short8*)(vcur + (nt * 16 + l15) * 64 + sw);
                    acc_o0[nt] = __builtin_amdgcn_mfma_f32_16x16x32_bf16(pf0[ks], bv, acc_o0[nt], 0, 0, 0);
                    acc_o1[nt] = __builtin_amdgcn_mfma_f32_16x16x32_bf16(pf1[ks], bv, acc_o1[nt], 0, 0, 0);
                }
            }
            __builtin_amdgcn_s_setprio(0);
        }

        float inv0[4], inv1[4];
        #pragma unroll
        for (int r = 0; r < 4; ++r) {
            float sm0 = rs0[r], sm1 = rs1[r];
            #pragma unroll
            for (int off = 1; off < 16; off <<= 1) {
                sm0 += __shfl_xor(sm0, off, 64);
                sm1 += __shfl_xor(sm1, off, 64);
            }
            inv0[r] = 1.0f / sm0;
            inv1[r] = 1.0f / sm1;
        }

        #pragma unroll
        for (int nt = 0; nt < 4; ++nt) {
            #pragma unroll
            for (int r = 0; r < 4; ++r) {
                int qr = q0 + w * 16 + quad * 4 + r;
                int hd = nt * 16 + l15;
                O[((size_t)bb * S_LEN + qr) * DMODEL + h * HDIM + hd] = f2bf(acc_o0[nt][r] * inv0[r]);
                O[((size_t)bb * S_LEN + qr + 64) * DMODEL + h * HDIM + hd] = f2bf(acc_o1[nt][r] * inv1[r]);
            }
        }
    }
}

extern "C" void kernel_launch(void* const* d_in, const int* in_sizes, int n_in,
                              void* d_out, int out_size, void* d_ws, size_t ws_size,
                              hipStream_t stream)
{
    const float* x    = (const float*)d_in[0];
    const float* ln1g = (const float*)d_in[2];
    const float* ln1b = (const float*)d_in[3];
    const float* wqkv = (const float*)d_in[4];
    const float* bqkv = (const float*)d_in[5];
    const float* wao  = (const float*)d_in[6];
    const float* bao  = (const float*)d_in[7];
    const float* ln2g = (const float*)d_in[8];
    const float* ln2b = (const float*)d_in[9];
    const float* wfc  = (const float*)d_in[10];
    const float* bfc  = (const float*)d_in[11];
    const float* wout = (const float*)d_in[12];
    const float* bout = (const float*)d_in[13];
    float* out = (float*)d_out;

    char* ws = (char*)d_ws;
    u16* wqkvT = (u16*)(ws + 0);          //  6.3 MB
    u16* waoT  = (u16*)(ws + 6291456);    //  2.1 MB
    u16* wfcT  = (u16*)(ws + 8388608);    //  8.4 MB
    u16* woutT = (u16*)(ws + 16777216);   //  8.4 MB
    u16* hb    = (u16*)(ws + 25165824);   // 16.8 MB: LN1 out; attn out; later h2
    u16* QKVb  = (u16*)(ws + 41943040);   // 50.3 MB: Q|K each 8.4M elements (V slot unused)
    u16* Vtb   = (u16*)(ws + 92274688);   // 16.8 MB: V^T (written directly by gemm_bt<0>)
    u16* Gb    = (u16*)(ws + 41943040);   // 67.1 MB: GELU out (QKV+Vt dead by then)

    u16* Qb   = QKVb;
    u16* Kbuf = QKVb + 8388608;

    transpose_cast<<<dim3(3072/32, 1024/32), dim3(32, 8), 0, stream>>>(wqkv, wqkvT, 1024, 3072);
    transpose_cast<<<dim3(1024/32, 1024/32), dim3(32, 8), 0, stream>>>(wao,  waoT,  1024, 1024);
    transpose_cast<<<dim3(4096/32, 1024/32), dim3(32, 8), 0, stream>>>(wfc,  wfcT,  1024, 4096);
    transpose_cast<<<dim3(1024/32, 4096/32), dim3(32, 8), 0, stream>>>(wout, woutT, 4096, 1024);

    ln_kernel<<<8192, 256, 0, stream>>>(x, ln1g, ln1b, hb);

    gemm_bt<0><<<dim3(3072/128, 8192/128), 256, 0, stream>>>(
        hb, wqkvT, 8192, 3072, 1024, bqkv, nullptr, nullptr, QKVb, Vtb, nullptr);

    flash_attn<<<dim3(64, 8), 256, 0, stream>>>(Qb, Kbuf, Vtb, hb);

    gemm_bt<1><<<dim3(1024/128, 8192/128), 256, 0, stream>>>(
        hb, waoT, 8192, 1024, 1024, bao, x, out, nullptr, nullptr, nullptr);

    ln_kernel<<<8192, 256, 0, stream>>>(out, ln2g, ln2b, hb);

    gemm256<2><<<dim3(4096/256, 8192/256), 512, 0, stream>>>(
        hb, wfcT, 8192, 4096, 1024, bfc, Gb, nullptr);

    gemm_bt<3><<<dim3(1024/128, 8192/128), 256, 0, stream>>>(
        Gb, woutT, 8192, 1024, 4096, bout, out, out, nullptr, nullptr, nullptr);
}

// Round 9
// 484.552 us; speedup vs baseline: 1.0546x; 1.0190x over previous
//
#include <hip/hip_runtime.h>

typedef unsigned short u16;
typedef __attribute__((ext_vector_type(8))) short short8;
typedef __attribute__((ext_vector_type(4))) float floatx4;
typedef __attribute__((ext_vector_type(4))) unsigned short ushort4_t;

#define S_LEN 2048
#define DMODEL 1024
#define NHEAD 16
#define HDIM 64

__device__ __forceinline__ u16 f2bf(float f) {
    union { float f; unsigned u; } v; v.f = f;
    unsigned u = v.u;
    unsigned r = (u + 0x7fffu + ((u >> 16) & 1u)) >> 16;
    return (u16)r;
}

// round-half-up bf16 pack (2 VALU ops) — for GEMM-feeding intermediates
__device__ __forceinline__ u16 f2bf_fast(float f) {
    union { float f; unsigned u; } v; v.f = f;
    return (u16)((v.u + 0x8000u) >> 16);
}

__device__ __forceinline__ void gld_lds16(const u16* g, u16* l) {
    __builtin_amdgcn_global_load_lds((const __attribute__((address_space(1))) void*)g,
                                     (__attribute__((address_space(3))) void*)l,
                                     16, 0, 0);
}

// ---------------- LayerNorm -> bf16 (used standalone for LN2) ----------------
__global__ __launch_bounds__(256) void ln_kernel(
    const float* __restrict__ x, const float* __restrict__ g,
    const float* __restrict__ b, u16* __restrict__ out)
{
    int row = blockIdx.x;
    int tid = threadIdx.x;
    const float4* xr = (const float4*)(x + (size_t)row * DMODEL);
    float4 v = xr[tid];
    float s  = v.x + v.y + v.z + v.w;
    float s2 = v.x * v.x + v.y * v.y + v.z * v.z + v.w * v.w;
    #pragma unroll
    for (int off = 1; off < 64; off <<= 1) {
        s  += __shfl_xor(s, off, 64);
        s2 += __shfl_xor(s2, off, 64);
    }
    __shared__ float red[2][4];
    int w = tid >> 6, lane = tid & 63;
    if (lane == 0) { red[0][w] = s; red[1][w] = s2; }
    __syncthreads();
    s  = red[0][0] + red[0][1] + red[0][2] + red[0][3];
    s2 = red[1][0] + red[1][1] + red[1][2] + red[1][3];
    float mu  = s * (1.0f / DMODEL);
    float var = s2 * (1.0f / DMODEL) - mu * mu;
    float inv = rsqrtf(var + 1e-5f);
    const float4* gr = (const float4*)g;
    const float4* br = (const float4*)b;
    float4 gv = gr[tid], bv = br[tid];
    u16* o = out + (size_t)row * DMODEL + tid * 4;
    o[0] = f2bf((v.x - mu) * inv * gv.x + bv.x);
    o[1] = f2bf((v.y - mu) * inv * gv.y + bv.y);
    o[2] = f2bf((v.z - mu) * inv * gv.z + bv.z);
    o[3] = f2bf((v.w - mu) * inv * gv.w + bv.w);
}

// ---------------- prep: LN1 + 4 weight transposes in ONE launch ----------------
// Replaces 5 independent launches (saves ~4x per-launch gap). Segments:
//  [0,8192):       LN1 rows (body identical to ln_kernel)
//  [8192,11264):   wqkv 1024x3072  (96 x-tiles x 32 y-tiles)
//  [11264,12288):  wao  1024x1024  (32 x 32)
//  [12288,16384):  wfc  1024x4096  (128 x 32)
//  [16384,20480):  wout 4096x1024  (32 x 128)
// Branch is block-uniform; both sub-bodies are byte-identical to the verified
// standalone kernels (thread mapping x=tid&31,y=tid>>5 == dim3(32,8) linear).
__global__ __launch_bounds__(256) void prep_kernel(
    const float* __restrict__ x, const float* __restrict__ g,
    const float* __restrict__ b, u16* __restrict__ out,
    const float* __restrict__ w0, u16* __restrict__ d0,
    const float* __restrict__ w1, u16* __restrict__ d1,
    const float* __restrict__ w2, u16* __restrict__ d2,
    const float* __restrict__ w3, u16* __restrict__ d3)
{
    int id = blockIdx.x;
    int tid = threadIdx.x;
    if (id < 8192) {
        // ---- LN1 ----
        int row = id;
        const float4* xr = (const float4*)(x + (size_t)row * DMODEL);
        float4 v = xr[tid];
        float s  = v.x + v.y + v.z + v.w;
        float s2 = v.x * v.x + v.y * v.y + v.z * v.z + v.w * v.w;
        #pragma unroll
        for (int off = 1; off < 64; off <<= 1) {
            s  += __shfl_xor(s, off, 64);
            s2 += __shfl_xor(s2, off, 64);
        }
        __shared__ float red[2][4];
        int w = tid >> 6, lane = tid & 63;
        if (lane == 0) { red[0][w] = s; red[1][w] = s2; }
        __syncthreads();
        s  = red[0][0] + red[0][1] + red[0][2] + red[0][3];
        s2 = red[1][0] + red[1][1] + red[1][2] + red[1][3];
        float mu  = s * (1.0f / DMODEL);
        float var = s2 * (1.0f / DMODEL) - mu * mu;
        float inv = rsqrtf(var + 1e-5f);
        const float4* gr = (const float4*)g;
        const float4* br = (const float4*)b;
        float4 gv = gr[tid], bv = br[tid];
        u16* o = out + (size_t)row * DMODEL + tid * 4;
        o[0] = f2bf((v.x - mu) * inv * gv.x + bv.x);
        o[1] = f2bf((v.y - mu) * inv * gv.y + bv.y);
        o[2] = f2bf((v.z - mu) * inv * gv.z + bv.z);
        o[3] = f2bf((v.w - mu) * inv * gv.w + bv.w);
        return;
    }
    // ---- weight transpose + cast: wt[n][k] = bf16(w[k][n]) ----
    id -= 8192;
    __shared__ float t[32][33];
    const float* w; u16* wt; int K, N, bx, by;
    if (id < 3072)      { w = w0; wt = d0; K = 1024; N = 3072; bx = id % 96;  by = id / 96;  }
    else if (id < 4096) { id -= 3072; w = w1; wt = d1; K = 1024; N = 1024; bx = id & 31;  by = id >> 5; }
    else if (id < 8192) { id -= 4096; w = w2; wt = d2; K = 1024; N = 4096; bx = id & 127; by = id >> 7; }
    else                { id -= 8192; w = w3; wt = d3; K = 4096; N = 1024; bx = id & 31;  by = id >> 5; }
    int n0 = bx * 32, k0 = by * 32;
    int xx = tid & 31, yy = tid >> 5;
    #pragma unroll
    for (int j = yy; j < 32; j += 8)
        t[j][xx] = w[(size_t)(k0 + j) * N + n0 + xx];
    __syncthreads();
    #pragma unroll
    for (int j = yy; j < 32; j += 8)
        wt[(size_t)(n0 + j) * K + k0 + xx] = f2bf(t[xx][j]);
}

// ---------------- legacy 128^2 GEMM (QKV / AO / FC2) ----------------
// Single-barrier double-buffered K-loop; staging pointers incremented.
// MODE 0: QKV -> Q (*0.125 folded) and K in [BH,S,64] at o0; V DIRECTLY
//         transposed [BH,64,S] into o1 (4 consecutive s packed per store).
// MODE 1/3: fout = C + bias + res (fp32)
// MODE 2: o0 = bf16(gelu(C + bias))
template<int MODE>
__global__ __launch_bounds__(256) void gemm_bt(
    const u16* __restrict__ A, const u16* __restrict__ BT,
    int M, int N, int K,
    const float* __restrict__ bias, const float* __restrict__ res,
    float* __restrict__ fout,
    u16* __restrict__ o0, u16* __restrict__ o1, u16* __restrict__ o2)
{
    __shared__ __attribute__((aligned(16))) u16 As[2][128 * 64];
    __shared__ __attribute__((aligned(16))) u16 Bs[2][128 * 64];
    int tid = threadIdx.x;
    int lane = tid & 63, w = tid >> 6;
    int wm = (w >> 1) * 64, wn = (w & 1) * 64;
    int l15 = lane & 15, quad = lane >> 4;
    int rowBase = blockIdx.y * 128, colBase = blockIdx.x * 128;

    floatx4 acc[4][4] = {};

    const u16* pa[4];
    const u16* pbt[4];
    int scb[4];
    #pragma unroll
    for (int i = 0; i < 4; ++i) {
        int c  = i * 256 + tid;
        int r  = c >> 3;
        int cs = ((c & 7) ^ (r & 7)) * 8;            // swizzled source chunk
        pa[i]  = A  + (size_t)(rowBase + r) * K + cs;
        pbt[i] = BT + (size_t)(colBase + r) * K + cs;
        scb[i] = (i * 256 + (tid & 0xC0)) * 8;       // wave-uniform LDS base
    }

    int KT = K >> 6;

    #pragma unroll
    for (int i = 0; i < 4; ++i) {
        gld_lds16(pa[i],  &As[0][0] + scb[i]);
        gld_lds16(pbt[i], &Bs[0][0] + scb[i]);
    }

    for (int kt = 0; kt < KT; ++kt) {
        __syncthreads();

        if (kt + 1 < KT) {
            u16* abuf = &As[(kt + 1) & 1][0];
            u16* bbuf = &Bs[(kt + 1) & 1][0];
            #pragma unroll
            for (int i = 0; i < 4; ++i) {
                pa[i]  += 64;
                pbt[i] += 64;
                gld_lds16(pa[i],  abuf + scb[i]);
                gld_lds16(pbt[i], bbuf + scb[i]);
            }
        }

        const u16* as = &As[kt & 1][0];
        const u16* bs = &Bs[kt & 1][0];
        #pragma unroll
        for (int ks = 0; ks < 2; ++ks) {
            int sw = (((ks * 4 + quad) ^ (l15 & 7))) * 8;
            short8 af[4], bf[4];
            #pragma unroll
            for (int im = 0; im < 4; ++im)
                af[im] = *(const short8*)(as + (wm + im * 16 + l15) * 64 + sw);
            #pragma unroll
            for (int in = 0; in < 4; ++in)
                bf[in] = *(const short8*)(bs + (wn + in * 16 + l15) * 64 + sw);
            #pragma unroll
            for (int im = 0; im < 4; ++im)
                #pragma unroll
                for (int in = 0; in < 4; ++in)
                    acc[im][in] = __builtin_amdgcn_mfma_f32_16x16x32_bf16(af[im], bf[in], acc[im][in], 0, 0, 0);
        }
    }

    // epilogue
    if (MODE == 0) {
        int t = colBase >> 10;                 // uniform per block (q/k/v)
        int cb1023 = colBase & 1023;
        if (t == 2) {
            // V: write directly transposed [BH,64,S]; r=0..3 are consecutive s
            #pragma unroll
            for (int im = 0; im < 4; ++im) {
                int gr0 = rowBase + wm + im * 16 + quad * 4;
                int bb2 = gr0 >> 11, ss = gr0 & 2047;
                #pragma unroll
                for (int in = 0; in < 4; ++in) {
                    int gc = colBase + wn + in * 16 + l15;
                    int rr = cb1023 + wn + in * 16 + l15;
                    int hh = rr >> 6, hd = rr & 63;
                    float bv = bias[gc];
                    ushort4_t pk;
                    pk.x = f2bf_fast(acc[im][in][0] + bv);
                    pk.y = f2bf_fast(acc[im][in][1] + bv);
                    pk.z = f2bf_fast(acc[im][in][2] + bv);
                    pk.w = f2bf_fast(acc[im][in][3] + bv);
                    *(ushort4_t*)(o1 + ((size_t)(bb2 * NHEAD + hh) * HDIM + hd) * S_LEN + ss) = pk;
                }
            }
        } else {
            u16* qb = o0 + (size_t)t * 8388608;    // 8192*1024 elements per tensor
            float sc = (t == 0) ? 0.125f : 1.0f;   // fold softmax 1/sqrt(64) into Q
            #pragma unroll
            for (int im = 0; im < 4; ++im) {
                #pragma unroll
                for (int in = 0; in < 4; ++in) {
                    #pragma unroll
                    for (int r = 0; r < 4; ++r) {
                        int gr = rowBase + wm + im * 16 + quad * 4 + r;
                        int gc = colBase + wn + in * 16 + l15;
                        float v = (acc[im][in][r] + bias[gc]) * sc;
                        int rr = cb1023 + wn + in * 16 + l15;
                        int hh = rr >> 6, hd = rr & 63;
                        int bb2 = gr >> 11, ss = gr & 2047;
                        qb[(((size_t)(bb2 * NHEAD + hh) * S_LEN + ss) * HDIM) + hd] = f2bf_fast(v);
                    }
                }
            }
        }
    } else {
        #pragma unroll
        for (int im = 0; im < 4; ++im) {
            #pragma unroll
            for (int in = 0; in < 4; ++in) {
                #pragma unroll
                for (int r = 0; r < 4; ++r) {
                    int gr = rowBase + wm + im * 16 + quad * 4 + r;
                    int gc = colBase + wn + in * 16 + l15;
                    float v = acc[im][in][r] + bias[gc];
                    if (MODE == 2) {
                        float p = v * (1.59576912f + 0.07135481f * v * v);
                        float e = __expf(-p);
                        float gl = v * __builtin_amdgcn_rcpf(1.0f + e);
                        o0[(size_t)gr * N + gc] = f2bf_fast(gl);
                    } else {
                        fout[(size_t)gr * N + gc] = v + res[(size_t)gr * N + gc];
                    }
                }
            }
        }
    }
}

// ---------------- 256^2 8-phase GEMM (FC1 only: grid 16x32 = 2 full rounds) ----------------
// Verified passing in rounds 3/5/8 (88.6-88.8 us vs legacy 90.9 at this shape).
template<int MODE>
__global__ __launch_bounds__(512, 2) void gemm256(
    const u16* __restrict__ A, const u16* __restrict__ BT,
    int M, int N, int K,
    const float* __restrict__ bias,
    u16* __restrict__ o0, u16* __restrict__ o1)
{
    __shared__ __attribute__((aligned(16))) u16 As[2][2][128 * 64];
    __shared__ __attribute__((aligned(16))) u16 Bs[2][2][128 * 64];
    int tid = threadIdx.x;
    int lane = tid & 63, w = tid >> 6;
    int wrow = w >> 2, wcol = w & 3;
    int l15 = lane & 15, quad = lane >> 4;
    int rowBase = blockIdx.y * 256, colBase = blockIdx.x * 256;
    int nrb = (wcol & 1) * 64;

    int swz[2] = { (quad ^ (l15 & 7)) * 8, ((4 + quad) ^ (l15 & 7)) * 8 };

    int cid0 = tid, cid1 = 512 + tid;
    int r0 = cid0 >> 3, r1 = cid1 >> 3;
    unsigned cs0 = (unsigned)(((cid0 & 7) ^ (r0 & 7)) * 8);
    unsigned cs1 = (unsigned)(((cid1 & 7) ^ (r1 & 7)) * 8);
    unsigned aoff0 = (unsigned)((rowBase + r0) * K) + cs0;
    unsigned aoff1 = (unsigned)((rowBase + r1) * K) + cs1;
    unsigned boff0 = (unsigned)((colBase + r0) * K) + cs0;
    unsigned boff1 = (unsigned)((colBase + r1) * K) + cs1;
    unsigned ldo0 = (unsigned)(cid0 * 8), ldo1 = (unsigned)(cid1 * 8);
    unsigned hK = (unsigned)(128 * K);

    floatx4 acc[8][4] = {};
    short8 af[4][2], bfL[2][2], bfH[2][2];

    int KT = K >> 6;

#define STG_A(db, tt, h) do { unsigned tb_ = (unsigned)(tt) * 64u + (h) * hK;      \
    gld_lds16(A + aoff0 + tb_, &As[db][h][0] + ldo0);                              \
    gld_lds16(A + aoff1 + tb_, &As[db][h][0] + ldo1); } while (0)
#define STG_B(db, tt, h) do { unsigned tb_ = (unsigned)(tt) * 64u + (h) * hK;      \
    gld_lds16(BT + boff0 + tb_, &Bs[db][h][0] + ldo0);                             \
    gld_lds16(BT + boff1 + tb_, &Bs[db][h][0] + ldo1); } while (0)
#define LDS_A(buf, MFB) do { const u16* ap_ = &As[buf][wrow][0];                   \
    _Pragma("unroll") for (int m_ = 0; m_ < 4; ++m_) {                             \
      af[m_][0] = *(const short8*)(ap_ + (((MFB) + m_) * 16 + l15) * 64 + swz[0]); \
      af[m_][1] = *(const short8*)(ap_ + (((MFB) + m_) * 16 + l15) * 64 + swz[1]); } } while (0)
#define LDS_B(buf, NFP, dst) do { const u16* bp_ = &Bs[buf][wcol >> 1][0];         \
    _Pragma("unroll") for (int n_ = 0; n_ < 2; ++n_) {                             \
      dst[n_][0] = *(const short8*)(bp_ + (nrb + ((NFP) * 2 + n_) * 16 + l15) * 64 + swz[0]); \
      dst[n_][1] = *(const short8*)(bp_ + (nrb + ((NFP) * 2 + n_) * 16 + l15) * 64 + swz[1]); } } while (0)
#define MFMA_Q(MFB, NFP, bsrc) do { __builtin_amdgcn_s_setprio(1);                 \
    _Pragma("unroll") for (int m_ = 0; m_ < 4; ++m_)                               \
    _Pragma("unroll") for (int n_ = 0; n_ < 2; ++n_) {                             \
      acc[(MFB) + m_][(NFP) * 2 + n_] = __builtin_amdgcn_mfma_f32_16x16x32_bf16(af[m_][0], bsrc[n_][0], acc[(MFB) + m_][(NFP) * 2 + n_], 0, 0, 0); \
      acc[(MFB) + m_][(NFP) * 2 + n_] = __builtin_amdgcn_mfma_f32_16x16x32_bf16(af[m_][1], bsrc[n_][1], acc[(MFB) + m_][(NFP) * 2 + n_], 0, 0, 0); } \
    __builtin_amdgcn_s_setprio(0); } while (0)
#define PH_MID() do { __builtin_amdgcn_sched_barrier(0);                           \
    __builtin_amdgcn_s_barrier();                                                  \
    asm volatile("s_waitcnt lgkmcnt(0)" ::: "memory");                             \
    __builtin_amdgcn_sched_barrier(0); } while (0)
#define PH_END() do { __builtin_amdgcn_sched_barrier(0);                           \
    __builtin_amdgcn_s_barrier(); } while (0)

    STG_A(0, 0, 0); STG_A(0, 0, 1);
    STG_B(0, 0, 0); STG_B(0, 0, 1);
    STG_B(1, 1, 0); STG_B(1, 1, 1);
    STG_A(1, 1, 0);
    asm volatile("s_waitcnt vmcnt(6)" ::: "memory");
    __builtin_amdgcn_s_barrier();

    for (int t = 0; t < KT; t += 2) {
        int t2 = (t + 2 < KT) ? t + 2 : KT - 1;
        int t3 = (t + 3 < KT) ? t + 3 : KT - 1;

        LDS_A(0, 0); LDS_B(0, 0, bfL);
        STG_A(1, t + 1, 1);
        asm volatile("s_waitcnt lgkmcnt(8)" ::: "memory");
        PH_MID(); MFMA_Q(0, 0, bfL); PH_END();

        LDS_B(0, 1, bfH);
        PH_MID(); MFMA_Q(0, 1, bfH); PH_END();

        LDS_A(0, 4);
        STG_B(0, t2, 0);
        PH_MID(); MFMA_Q(4, 1, bfH); PH_END();

        STG_B(0, t2, 1);
        STG_A(0, t2, 0);
        asm volatile("s_waitcnt vmcnt(6)" ::: "memory");
        PH_MID(); MFMA_Q(4, 0, bfL); PH_END();

        LDS_A(1, 0); LDS_B(1, 0, bfL);
        STG_A(0, t2, 1);
        asm volatile("s_waitcnt lgkmcnt(8)" ::: "memory");
        PH_MID(); MFMA_Q(0, 0, bfL); PH_END();

        LDS_B(1, 1, bfH);
        PH_MID(); MFMA_Q(0, 1, bfH); PH_END();

        LDS_A(1, 4);
        STG_B(1, t3, 0);
        PH_MID(); MFMA_Q(4, 1, bfH); PH_END();

        STG_B(1, t3, 1);
        STG_A(1, t3, 0);
        asm volatile("s_waitcnt vmcnt(6)" ::: "memory");
        PH_MID(); MFMA_Q(4, 0, bfL); PH_END();
    }
    asm volatile("s_waitcnt vmcnt(0)" ::: "memory");

#undef STG_A
#undef STG_B
#undef LDS_A
#undef LDS_B
#undef MFMA_Q
#undef PH_MID
#undef PH_END

    int wr0 = rowBase + wrow * 128 + quad * 4;
    int wc0 = colBase + wcol * 64 + l15;
    // MODE 2: GELU -> bf16 row-major (FC1)
    #pragma unroll
    for (int mf = 0; mf < 8; ++mf) {
        #pragma unroll
        for (int nf = 0; nf < 4; ++nf) {
            int gc = wc0 + nf * 16;
            float bv = bias[gc];
            #pragma unroll
            for (int r = 0; r < 4; ++r) {
                int gr = wr0 + mf * 16 + r;
                float v = acc[mf][nf][r] + bv;
                float p = v * (1.59576912f + 0.07135481f * v * v);
                float e = __expf(-p);
                float gl = v * __builtin_amdgcn_rcpf(1.0f + e);
                o0[(size_t)gr * N + gc] = f2bf_fast(gl);
            }
        }
    }
}

// ---------------- flash attention (causal), bf16 in/out ----------------
// Fixed-max softmax (scale pre-folded into Q). Macro Q-tile = 128 rows/block;
// each wave owns TWO 16-row strips 64 apart, so every K/V ds_read_b128 feeds
// MFMAs for 32 q-rows. Blocks handle macros {p, 15-p} -> 34 K-iters each.
// Grid (bh=64, p=8): ID%8 = bh%8 -> all p-blocks of one head share one XCD L2.
__global__ __launch_bounds__(256) void flash_attn(
    const u16* __restrict__ Q, const u16* __restrict__ Kb,
    const u16* __restrict__ Vt, u16* __restrict__ O)
{
    __shared__ __attribute__((aligned(16))) u16 Ks[2][64 * 64];
    __shared__ __attribute__((aligned(16))) u16 Vs[2][64 * 64];
    __shared__ __attribute__((aligned(16))) u16 Pl[4][2][16][64];
    int tid = threadIdx.x;
    int lane = tid & 63, w = tid >> 6;
    int l15 = lane & 15, quad = lane >> 4;
    int bh = blockIdx.x;           // 0..63 (fastest-varying -> XCD = bh%8)
    int pp = blockIdx.y;           // 0..7
    int bb = bh >> 4, h = bh & 15;

    const u16* Kp0 = Kb + (size_t)bh * S_LEN * HDIM;
    const u16* Vp  = Vt + (size_t)bh * HDIM * S_LEN;

    int rstage = lane >> 3;                       // 0..7
    int cstage = ((lane & 7) ^ rstage) * 8;       // swizzled source chunk (u16 units)
    int vrow0  = w * 8 + rstage;                  // staging row within 32-row half

    int ms[2] = {pp, 15 - pp};
    int pb = 0;

    // prologue: stage K/V tile kt=0 into parity 0
    #pragma unroll
    for (int i = 0; i < 2; ++i) {
        int row = i * 32 + vrow0;
        gld_lds16(Kp0 + row * HDIM + cstage, &Ks[0][0] + i * 2048 + w * 512);
        gld_lds16(Vp + (size_t)row * S_LEN + cstage, &Vs[0][0] + i * 2048 + w * 512);
    }

    #pragma unroll 1
    for (int sel = 0; sel < 2; ++sel) {
        int m = ms[sel];
        int q0 = m * 128;

        const u16* Qp = Q + ((size_t)bh * S_LEN + q0 + w * 16) * HDIM;
        short8 aq0[2], aq1[2];
        #pragma unroll
        for (int ks = 0; ks < 2; ++ks) {
            aq0[ks] = *(const short8*)(Qp + l15 * HDIM + ks * 32 + quad * 8);
            aq1[ks] = *(const short8*)(Qp + 64 * HDIM + l15 * HDIM + ks * 32 + quad * 8);
        }

        floatx4 acc_o0[4] = {}, acc_o1[4] = {};
        float rs0[4] = {0.f, 0.f, 0.f, 0.f};
        float rs1[4] = {0.f, 0.f, 0.f, 0.f};

        int KT = 2 * m + 2;   // K-tiles this macro (strip1 needs kt <= 2m+1)

        auto softmax_store = [&](floatx4 (&sa)[4], float (&rs)[4], int st, bool diag) {
            #pragma unroll
            for (int nt = 0; nt < 4; ++nt) {
                int wc = nt * 16 + l15;
                int wchunk = wc >> 3, woff = wc & 7;
                #pragma unroll
                for (int r = 0; r < 4; ++r) {
                    float sv = sa[nt][r];           // scale already folded into Q
                    if (diag) {
                        int qr = w * 16 + quad * 4 + r;
                        if (wc > qr) sv = -1e30f;
                    }
                    float pv = __expf(sv);          // fixed-max softmax; exp(-1e30)=0
                    rs[r] += pv;
                    int row = quad * 4 + r;
                    Pl[w][st][row][((wchunk ^ (row & 7)) << 3) + woff] = f2bf_fast(pv);
                }
            }
        };

        #pragma unroll 1
        for (int kt = 0; kt < KT; ++kt) {
            __syncthreads();   // tile kt (parity pb) resident; drain covered by prior phase
            int cur = pb;

            int nk = (kt + 1 < KT) ? (kt + 1) : ((sel < 1) ? 0 : -1);
            if (nk >= 0) {
                pb ^= 1;
                const u16* Kg = Kp0 + (size_t)nk * 64 * HDIM;
                const u16* Vg = Vp + nk * 64;
                u16* kb_ = &Ks[pb][0];
                u16* vb_ = &Vs[pb][0];
                #pragma unroll
                for (int i = 0; i < 2; ++i) {
                    int row = i * 32 + vrow0;
                    gld_lds16(Kg + row * HDIM + cstage, kb_ + i * 2048 + w * 512);
                    gld_lds16(Vg + (size_t)row * S_LEN + cstage, vb_ + i * 2048 + w * 512);
                }
            }

            const u16* kcur = &Ks[cur][0];
            const u16* vcur = &Vs[cur][0];

            bool a0 = (kt < KT - 1);      // strip0 active (kt <= 2m)

            floatx4 s0a[4] = {}, s1a[4] = {};
            __builtin_amdgcn_s_setprio(1);
            #pragma unroll
            for (int nt = 0; nt < 4; ++nt) {
                #pragma unroll
                for (int ks = 0; ks < 2; ++ks) {
                    int sw = ((ks * 4 + quad) ^ (l15 & 7)) * 8;
                    short8 bk = *(const short8*)(kcur + (nt * 16 + l15) * 64 + sw);
                    s0a[nt] = __builtin_amdgcn_mfma_f32_16x16x32_bf16(aq0[ks], bk, s0a[nt], 0, 0, 0);
                    s1a[nt] = __builtin_amdgcn_mfma_f32_16x16x32_bf16(aq1[ks], bk, s1a[nt], 0, 0, 0);
                }
            }
            __builtin_amdgcn_s_setprio(0);

            if (a0) softmax_store(s0a, rs0, 0, kt == KT - 2);
            softmax_store(s1a, rs1, 1, kt == KT - 1);

            short8 pf0[2] = {}, pf1[2];
            if (a0) {
                #pragma unroll
                for (int ks = 0; ks < 2; ++ks) {
                    int pc = ((ks * 4 + quad) ^ (l15 & 7)) * 8;
                    pf0[ks] = *(const short8*)(&Pl[w][0][l15][pc]);
                }
            }
            #pragma unroll
            for (int ks = 0; ks < 2; ++ks) {
                int pc = ((ks * 4 + quad) ^ (l15 & 7)) * 8;
                pf1[ks] = *(const short8*)(&Pl[w][1][l15][pc]);
            }

            __builtin_amdgcn_s_setprio(1);
            #pragma unroll
            for (int nt = 0; nt < 4; ++nt) {
                #pragma unroll
                for (int ks = 0; ks < 2; ++ks) {
                    int sw = ((ks * 4 + quad) ^ (l15 & 7)) * 8;
                    short8 bv = *(const short8*)(vcur + (nt * 16 + l15) * 64 + sw);
                    acc_o0[nt] = __builtin_amdgcn_mfma_f32_16x16x32_bf16(pf0[ks], bv, acc_o0[nt], 0, 0, 0);
                    acc_o1[nt] = __builtin_amdgcn_mfma_f32_16x16x32_bf16(pf1[ks], bv, acc_o1[nt], 0, 0, 0);
                }
            }
            __builtin_amdgcn_s_setprio(0);
        }

        float inv0[4], inv1[4];
        #pragma unroll
        for (int r = 0; r < 4; ++r) {
            float sm0 = rs0[r], sm1 = rs1[r];
            #pragma unroll
            for (int off = 1; off < 16; off <<= 1) {
                sm0 += __shfl_xor(sm0, off, 64);
                sm1 += __shfl_xor(sm1, off, 64);
            }
            inv0[r] = 1.0f / sm0;
            inv1[r] = 1.0f / sm1;
        }

        #pragma unroll
        for (int nt = 0; nt < 4; ++nt) {
            #pragma unroll
            for (int r = 0; r < 4; ++r) {
                int qr = q0 + w * 16 + quad * 4 + r;
                int hd = nt * 16 + l15;
                O[((size_t)bb * S_LEN + qr) * DMODEL + h * HDIM + hd] = f2bf(acc_o0[nt][r] * inv0[r]);
                O[((size_t)bb * S_LEN + qr + 64) * DMODEL + h * HDIM + hd] = f2bf(acc_o1[nt][r] * inv1[r]);
            }
        }
    }
}

extern "C" void kernel_launch(void* const* d_in, const int* in_sizes, int n_in,
                              void* d_out, int out_size, void* d_ws, size_t ws_size,
                              hipStream_t stream)
{
    const float* x    = (const float*)d_in[0];
    const float* ln1g = (const float*)d_in[2];
    const float* ln1b = (const float*)d_in[3];
    const float* wqkv = (const float*)d_in[4];
    const float* bqkv = (const float*)d_in[5];
    const float* wao  = (const float*)d_in[6];
    const float* bao  = (const float*)d_in[7];
    const float* ln2g = (const float*)d_in[8];
    const float* ln2b = (const float*)d_in[9];
    const float* wfc  = (const float*)d_in[10];
    const float* bfc  = (const float*)d_in[11];
    const float* wout = (const float*)d_in[12];
    const float* bout = (const float*)d_in[13];
    float* out = (float*)d_out;

    char* ws = (char*)d_ws;
    u16* wqkvT = (u16*)(ws + 0);          //  6.3 MB
    u16* waoT  = (u16*)(ws + 6291456);    //  2.1 MB
    u16* wfcT  = (u16*)(ws + 8388608);    //  8.4 MB
    u16* woutT = (u16*)(ws + 16777216);   //  8.4 MB
    u16* hb    = (u16*)(ws + 25165824);   // 16.8 MB: LN1 out; attn out; later h2
    u16* QKVb  = (u16*)(ws + 41943040);   // 50.3 MB: Q|K each 8.4M elements (V slot unused)
    u16* Vtb   = (u16*)(ws + 92274688);   // 16.8 MB: V^T (written directly by gemm_bt<0>)
    u16* Gb    = (u16*)(ws + 41943040);   // 67.1 MB: GELU out (QKV+Vt dead by then)

    u16* Qb   = QKVb;
    u16* Kbuf = QKVb + 8388608;

    // one launch: LN1 + all 4 weight transposes (all depend only on inputs)
    prep_kernel<<<dim3(20480), 256, 0, stream>>>(
        x, ln1g, ln1b, hb,
        wqkv, wqkvT, wao, waoT, wfc, wfcT, wout, woutT);

    gemm_bt<0><<<dim3(3072/128, 8192/128), 256, 0, stream>>>(
        hb, wqkvT, 8192, 3072, 1024, bqkv, nullptr, nullptr, QKVb, Vtb, nullptr);

    flash_attn<<<dim3(64, 8), 256, 0, stream>>>(Qb, Kbuf, Vtb, hb);

    gemm_bt<1><<<dim3(1024/128, 8192/128), 256, 0, stream>>>(
        hb, waoT, 8192, 1024, 1024, bao, x, out, nullptr, nullptr, nullptr);

    ln_kernel<<<8192, 256, 0, stream>>>(out, ln2g, ln2b, hb);

    gemm256<2><<<dim3(4096/256, 8192/256), 512, 0, stream>>>(
        hb, wfcT, 8192, 4096, 1024, bfc, Gb, nullptr);

    gemm_bt<3><<<dim3(1024/128, 8192/128), 256, 0, stream>>>(
        Gb, woutT, 8192, 1024, 4096, bout, out, out, nullptr, nullptr, nullptr);
}

// Round 10
// 480.196 us; speedup vs baseline: 1.0642x; 1.0091x over previous
//
#include <hip/hip_runtime.h>

typedef unsigned short u16;
typedef __attribute__((ext_vector_type(8))) short short8;
typedef __attribute__((ext_vector_type(4))) float floatx4;
typedef __attribute__((ext_vector_type(4))) unsigned short ushort4_t;

#define S_LEN 2048
#define DMODEL 1024
#define NHEAD 16
#define HDIM 64

__device__ __forceinline__ u16 f2bf(float f) {
    union { float f; unsigned u; } v; v.f = f;
    unsigned u = v.u;
    unsigned r = (u + 0x7fffu + ((u >> 16) & 1u)) >> 16;
    return (u16)r;
}

// round-half-up bf16 pack (2 VALU ops) — for GEMM-feeding intermediates
__device__ __forceinline__ u16 f2bf_fast(float f) {
    union { float f; unsigned u; } v; v.f = f;
    return (u16)((v.u + 0x8000u) >> 16);
}

__device__ __forceinline__ void gld_lds16(const u16* g, u16* l) {
    __builtin_amdgcn_global_load_lds((const __attribute__((address_space(1))) void*)g,
                                     (__attribute__((address_space(3))) void*)l,
                                     16, 0, 0);
}

// ---------------- LayerNorm -> bf16 (used standalone for LN2) ----------------
__global__ __launch_bounds__(256) void ln_kernel(
    const float* __restrict__ x, const float* __restrict__ g,
    const float* __restrict__ b, u16* __restrict__ out)
{
    int row = blockIdx.x;
    int tid = threadIdx.x;
    const float4* xr = (const float4*)(x + (size_t)row * DMODEL);
    float4 v = xr[tid];
    float s  = v.x + v.y + v.z + v.w;
    float s2 = v.x * v.x + v.y * v.y + v.z * v.z + v.w * v.w;
    #pragma unroll
    for (int off = 1; off < 64; off <<= 1) {
        s  += __shfl_xor(s, off, 64);
        s2 += __shfl_xor(s2, off, 64);
    }
    __shared__ float red[2][4];
    int w = tid >> 6, lane = tid & 63;
    if (lane == 0) { red[0][w] = s; red[1][w] = s2; }
    __syncthreads();
    s  = red[0][0] + red[0][1] + red[0][2] + red[0][3];
    s2 = red[1][0] + red[1][1] + red[1][2] + red[1][3];
    float mu  = s * (1.0f / DMODEL);
    float var = s2 * (1.0f / DMODEL) - mu * mu;
    float inv = rsqrtf(var + 1e-5f);
    const float4* gr = (const float4*)g;
    const float4* br = (const float4*)b;
    float4 gv = gr[tid], bv = br[tid];
    u16* o = out + (size_t)row * DMODEL + tid * 4;
    o[0] = f2bf((v.x - mu) * inv * gv.x + bv.x);
    o[1] = f2bf((v.y - mu) * inv * gv.y + bv.y);
    o[2] = f2bf((v.z - mu) * inv * gv.z + bv.z);
    o[3] = f2bf((v.w - mu) * inv * gv.w + bv.w);
}

// ---------------- prep: LN1 + 4 weight transposes in ONE launch ----------------
// Verified passing in r9. Segments:
//  [0,8192): LN1 rows | [8192,11264): wqkv | [11264,12288): wao
//  [12288,16384): wfc | [16384,20480): wout
__global__ __launch_bounds__(256) void prep_kernel(
    const float* __restrict__ x, const float* __restrict__ g,
    const float* __restrict__ b, u16* __restrict__ out,
    const float* __restrict__ w0, u16* __restrict__ d0,
    const float* __restrict__ w1, u16* __restrict__ d1,
    const float* __restrict__ w2, u16* __restrict__ d2,
    const float* __restrict__ w3, u16* __restrict__ d3)
{
    int id = blockIdx.x;
    int tid = threadIdx.x;
    if (id < 8192) {
        // ---- LN1 ----
        int row = id;
        const float4* xr = (const float4*)(x + (size_t)row * DMODEL);
        float4 v = xr[tid];
        float s  = v.x + v.y + v.z + v.w;
        float s2 = v.x * v.x + v.y * v.y + v.z * v.z + v.w * v.w;
        #pragma unroll
        for (int off = 1; off < 64; off <<= 1) {
            s  += __shfl_xor(s, off, 64);
            s2 += __shfl_xor(s2, off, 64);
        }
        __shared__ float red[2][4];
        int w = tid >> 6, lane = tid & 63;
        if (lane == 0) { red[0][w] = s; red[1][w] = s2; }
        __syncthreads();
        s  = red[0][0] + red[0][1] + red[0][2] + red[0][3];
        s2 = red[1][0] + red[1][1] + red[1][2] + red[1][3];
        float mu  = s * (1.0f / DMODEL);
        float var = s2 * (1.0f / DMODEL) - mu * mu;
        float inv = rsqrtf(var + 1e-5f);
        const float4* gr = (const float4*)g;
        const float4* br = (const float4*)b;
        float4 gv = gr[tid], bv = br[tid];
        u16* o = out + (size_t)row * DMODEL + tid * 4;
        o[0] = f2bf((v.x - mu) * inv * gv.x + bv.x);
        o[1] = f2bf((v.y - mu) * inv * gv.y + bv.y);
        o[2] = f2bf((v.z - mu) * inv * gv.z + bv.z);
        o[3] = f2bf((v.w - mu) * inv * gv.w + bv.w);
        return;
    }
    // ---- weight transpose + cast: wt[n][k] = bf16(w[k][n]) ----
    id -= 8192;
    __shared__ float t[32][33];
    const float* w; u16* wt; int K, N, bx, by;
    if (id < 3072)      { w = w0; wt = d0; K = 1024; N = 3072; bx = id % 96;  by = id / 96;  }
    else if (id < 4096) { id -= 3072; w = w1; wt = d1; K = 1024; N = 1024; bx = id & 31;  by = id >> 5; }
    else if (id < 8192) { id -= 4096; w = w2; wt = d2; K = 1024; N = 4096; bx = id & 127; by = id >> 7; }
    else                { id -= 8192; w = w3; wt = d3; K = 4096; N = 1024; bx = id & 31;  by = id >> 5; }
    int n0 = bx * 32, k0 = by * 32;
    int xx = tid & 31, yy = tid >> 5;
    #pragma unroll
    for (int j = yy; j < 32; j += 8)
        t[j][xx] = w[(size_t)(k0 + j) * N + n0 + xx];
    __syncthreads();
    #pragma unroll
    for (int j = yy; j < 32; j += 8)
        wt[(size_t)(n0 + j) * K + k0 + xx] = f2bf(t[xx][j]);
}

// ---------------- legacy 128^2 GEMM (QKV / AO / FC2) ----------------
// Single-barrier double-buffered K-loop; staging pointers incremented.
// MODE 0: QKV -> Q (*0.125 folded) and K in [BH,S,64] at o0; V DIRECTLY
//         transposed [BH,64,S] into o1 (4 consecutive s packed per store).
// MODE 1/3: fout = C + bias + res (fp32)
// MODE 2: o0 = bf16(gelu(C + bias))
template<int MODE>
__global__ __launch_bounds__(256) void gemm_bt(
    const u16* __restrict__ A, const u16* __restrict__ BT,
    int M, int N, int K,
    const float* __restrict__ bias, const float* __restrict__ res,
    float* __restrict__ fout,
    u16* __restrict__ o0, u16* __restrict__ o1, u16* __restrict__ o2)
{
    __shared__ __attribute__((aligned(16))) u16 As[2][128 * 64];
    __shared__ __attribute__((aligned(16))) u16 Bs[2][128 * 64];
    int tid = threadIdx.x;
    int lane = tid & 63, w = tid >> 6;
    int wm = (w >> 1) * 64, wn = (w & 1) * 64;
    int l15 = lane & 15, quad = lane >> 4;
    int rowBase = blockIdx.y * 128, colBase = blockIdx.x * 128;

    floatx4 acc[4][4] = {};

    const u16* pa[4];
    const u16* pbt[4];
    int scb[4];
    #pragma unroll
    for (int i = 0; i < 4; ++i) {
        int c  = i * 256 + tid;
        int r  = c >> 3;
        int cs = ((c & 7) ^ (r & 7)) * 8;            // swizzled source chunk
        pa[i]  = A  + (size_t)(rowBase + r) * K + cs;
        pbt[i] = BT + (size_t)(colBase + r) * K + cs;
        scb[i] = (i * 256 + (tid & 0xC0)) * 8;       // wave-uniform LDS base
    }

    int KT = K >> 6;

    #pragma unroll
    for (int i = 0; i < 4; ++i) {
        gld_lds16(pa[i],  &As[0][0] + scb[i]);
        gld_lds16(pbt[i], &Bs[0][0] + scb[i]);
    }

    for (int kt = 0; kt < KT; ++kt) {
        __syncthreads();

        if (kt + 1 < KT) {
            u16* abuf = &As[(kt + 1) & 1][0];
            u16* bbuf = &Bs[(kt + 1) & 1][0];
            #pragma unroll
            for (int i = 0; i < 4; ++i) {
                pa[i]  += 64;
                pbt[i] += 64;
                gld_lds16(pa[i],  abuf + scb[i]);
                gld_lds16(pbt[i], bbuf + scb[i]);
            }
        }

        const u16* as = &As[kt & 1][0];
        const u16* bs = &Bs[kt & 1][0];
        #pragma unroll
        for (int ks = 0; ks < 2; ++ks) {
            int sw = (((ks * 4 + quad) ^ (l15 & 7))) * 8;
            short8 af[4], bf[4];
            #pragma unroll
            for (int im = 0; im < 4; ++im)
                af[im] = *(const short8*)(as + (wm + im * 16 + l15) * 64 + sw);
            #pragma unroll
            for (int in = 0; in < 4; ++in)
                bf[in] = *(const short8*)(bs + (wn + in * 16 + l15) * 64 + sw);
            #pragma unroll
            for (int im = 0; im < 4; ++im)
                #pragma unroll
                for (int in = 0; in < 4; ++in)
                    acc[im][in] = __builtin_amdgcn_mfma_f32_16x16x32_bf16(af[im], bf[in], acc[im][in], 0, 0, 0);
        }
    }

    // epilogue
    if (MODE == 0) {
        int t = colBase >> 10;                 // uniform per block (q/k/v)
        int cb1023 = colBase & 1023;
        if (t == 2) {
            // V: write directly transposed [BH,64,S]; r=0..3 are consecutive s
            #pragma unroll
            for (int im = 0; im < 4; ++im) {
                int gr0 = rowBase + wm + im * 16 + quad * 4;
                int bb2 = gr0 >> 11, ss = gr0 & 2047;
                #pragma unroll
                for (int in = 0; in < 4; ++in) {
                    int gc = colBase + wn + in * 16 + l15;
                    int rr = cb1023 + wn + in * 16 + l15;
                    int hh = rr >> 6, hd = rr & 63;
                    float bv = bias[gc];
                    ushort4_t pk;
                    pk.x = f2bf_fast(acc[im][in][0] + bv);
                    pk.y = f2bf_fast(acc[im][in][1] + bv);
                    pk.z = f2bf_fast(acc[im][in][2] + bv);
                    pk.w = f2bf_fast(acc[im][in][3] + bv);
                    *(ushort4_t*)(o1 + ((size_t)(bb2 * NHEAD + hh) * HDIM + hd) * S_LEN + ss) = pk;
                }
            }
        } else {
            u16* qb = o0 + (size_t)t * 8388608;    // 8192*1024 elements per tensor
            float sc = (t == 0) ? 0.125f : 1.0f;   // fold softmax 1/sqrt(64) into Q
            #pragma unroll
            for (int im = 0; im < 4; ++im) {
                #pragma unroll
                for (int in = 0; in < 4; ++in) {
                    #pragma unroll
                    for (int r = 0; r < 4; ++r) {
                        int gr = rowBase + wm + im * 16 + quad * 4 + r;
                        int gc = colBase + wn + in * 16 + l15;
                        float v = (acc[im][in][r] + bias[gc]) * sc;
                        int rr = cb1023 + wn + in * 16 + l15;
                        int hh = rr >> 6, hd = rr & 63;
                        int bb2 = gr >> 11, ss = gr & 2047;
                        qb[(((size_t)(bb2 * NHEAD + hh) * S_LEN + ss) * HDIM) + hd] = f2bf_fast(v);
                    }
                }
            }
        }
    } else {
        #pragma unroll
        for (int im = 0; im < 4; ++im) {
            #pragma unroll
            for (int in = 0; in < 4; ++in) {
                #pragma unroll
                for (int r = 0; r < 4; ++r) {
                    int gr = rowBase + wm + im * 16 + quad * 4 + r;
                    int gc = colBase + wn + in * 16 + l15;
                    float v = acc[im][in][r] + bias[gc];
                    if (MODE == 2) {
                        float p = v * (1.59576912f + 0.07135481f * v * v);
                        float e = __expf(-p);
                        float gl = v * __builtin_amdgcn_rcpf(1.0f + e);
                        o0[(size_t)gr * N + gc] = f2bf_fast(gl);
                    } else {
                        fout[(size_t)gr * N + gc] = v + res[(size_t)gr * N + gc];
                    }
                }
            }
        }
    }
}

// ---------------- 256^2 8-phase GEMM (FC1 only: grid 16x32 = 2 full rounds) ----------------
// Verified passing in rounds 3/5/8/9 (88.5-89.6 us vs legacy 90.9 at this shape).
template<int MODE>
__global__ __launch_bounds__(512, 2) void gemm256(
    const u16* __restrict__ A, const u16* __restrict__ BT,
    int M, int N, int K,
    const float* __restrict__ bias,
    u16* __restrict__ o0, u16* __restrict__ o1)
{
    __shared__ __attribute__((aligned(16))) u16 As[2][2][128 * 64];
    __shared__ __attribute__((aligned(16))) u16 Bs[2][2][128 * 64];
    int tid = threadIdx.x;
    int lane = tid & 63, w = tid >> 6;
    int wrow = w >> 2, wcol = w & 3;
    int l15 = lane & 15, quad = lane >> 4;
    int rowBase = blockIdx.y * 256, colBase = blockIdx.x * 256;
    int nrb = (wcol & 1) * 64;

    int swz[2] = { (quad ^ (l15 & 7)) * 8, ((4 + quad) ^ (l15 & 7)) * 8 };

    int cid0 = tid, cid1 = 512 + tid;
    int r0 = cid0 >> 3, r1 = cid1 >> 3;
    unsigned cs0 = (unsigned)(((cid0 & 7) ^ (r0 & 7)) * 8);
    unsigned cs1 = (unsigned)(((cid1 & 7) ^ (r1 & 7)) * 8);
    unsigned aoff0 = (unsigned)((rowBase + r0) * K) + cs0;
    unsigned aoff1 = (unsigned)((rowBase + r1) * K) + cs1;
    unsigned boff0 = (unsigned)((colBase + r0) * K) + cs0;
    unsigned boff1 = (unsigned)((colBase + r1) * K) + cs1;
    unsigned ldo0 = (unsigned)(cid0 * 8), ldo1 = (unsigned)(cid1 * 8);
    unsigned hK = (unsigned)(128 * K);

    floatx4 acc[8][4] = {};
    short8 af[4][2], bfL[2][2], bfH[2][2];

    int KT = K >> 6;

#define STG_A(db, tt, h) do { unsigned tb_ = (unsigned)(tt) * 64u + (h) * hK;      \
    gld_lds16(A + aoff0 + tb_, &As[db][h][0] + ldo0);                              \
    gld_lds16(A + aoff1 + tb_, &As[db][h][0] + ldo1); } while (0)
#define STG_B(db, tt, h) do { unsigned tb_ = (unsigned)(tt) * 64u + (h) * hK;      \
    gld_lds16(BT + boff0 + tb_, &Bs[db][h][0] + ldo0);                             \
    gld_lds16(BT + boff1 + tb_, &Bs[db][h][0] + ldo1); } while (0)
#define LDS_A(buf, MFB) do { const u16* ap_ = &As[buf][wrow][0];                   \
    _Pragma("unroll") for (int m_ = 0; m_ < 4; ++m_) {                             \
      af[m_][0] = *(const short8*)(ap_ + (((MFB) + m_) * 16 + l15) * 64 + swz[0]); \
      af[m_][1] = *(const short8*)(ap_ + (((MFB) + m_) * 16 + l15) * 64 + swz[1]); } } while (0)
#define LDS_B(buf, NFP, dst) do { const u16* bp_ = &Bs[buf][wcol >> 1][0];         \
    _Pragma("unroll") for (int n_ = 0; n_ < 2; ++n_) {                             \
      dst[n_][0] = *(const short8*)(bp_ + (nrb + ((NFP) * 2 + n_) * 16 + l15) * 64 + swz[0]); \
      dst[n_][1] = *(const short8*)(bp_ + (nrb + ((NFP) * 2 + n_) * 16 + l15) * 64 + swz[1]); } } while (0)
#define MFMA_Q(MFB, NFP, bsrc) do { __builtin_amdgcn_s_setprio(1);                 \
    _Pragma("unroll") for (int m_ = 0; m_ < 4; ++m_)                               \
    _Pragma("unroll") for (int n_ = 0; n_ < 2; ++n_) {                             \
      acc[(MFB) + m_][(NFP) * 2 + n_] = __builtin_amdgcn_mfma_f32_16x16x32_bf16(af[m_][0], bsrc[n_][0], acc[(MFB) + m_][(NFP) * 2 + n_], 0, 0, 0); \
      acc[(MFB) + m_][(NFP) * 2 + n_] = __builtin_amdgcn_mfma_f32_16x16x32_bf16(af[m_][1], bsrc[n_][1], acc[(MFB) + m_][(NFP) * 2 + n_], 0, 0, 0); } \
    __builtin_amdgcn_s_setprio(0); } while (0)
#define PH_MID() do { __builtin_amdgcn_sched_barrier(0);                           \
    __builtin_amdgcn_s_barrier();                                                  \
    asm volatile("s_waitcnt lgkmcnt(0)" ::: "memory");                             \
    __builtin_amdgcn_sched_barrier(0); } while (0)
#define PH_END() do { __builtin_amdgcn_sched_barrier(0);                           \
    __builtin_amdgcn_s_barrier(); } while (0)

    STG_A(0, 0, 0); STG_A(0, 0, 1);
    STG_B(0, 0, 0); STG_B(0, 0, 1);
    STG_B(1, 1, 0); STG_B(1, 1, 1);
    STG_A(1, 1, 0);
    asm volatile("s_waitcnt vmcnt(6)" ::: "memory");
    __builtin_amdgcn_s_barrier();

    for (int t = 0; t < KT; t += 2) {
        int t2 = (t + 2 < KT) ? t + 2 : KT - 1;
        int t3 = (t + 3 < KT) ? t + 3 : KT - 1;

        LDS_A(0, 0); LDS_B(0, 0, bfL);
        STG_A(1, t + 1, 1);
        asm volatile("s_waitcnt lgkmcnt(8)" ::: "memory");
        PH_MID(); MFMA_Q(0, 0, bfL); PH_END();

        LDS_B(0, 1, bfH);
        PH_MID(); MFMA_Q(0, 1, bfH); PH_END();

        LDS_A(0, 4);
        STG_B(0, t2, 0);
        PH_MID(); MFMA_Q(4, 1, bfH); PH_END();

        STG_B(0, t2, 1);
        STG_A(0, t2, 0);
        asm volatile("s_waitcnt vmcnt(6)" ::: "memory");
        PH_MID(); MFMA_Q(4, 0, bfL); PH_END();

        LDS_A(1, 0); LDS_B(1, 0, bfL);
        STG_A(0, t2, 1);
        asm volatile("s_waitcnt lgkmcnt(8)" ::: "memory");
        PH_MID(); MFMA_Q(0, 0, bfL); PH_END();

        LDS_B(1, 1, bfH);
        PH_MID(); MFMA_Q(0, 1, bfH); PH_END();

        LDS_A(1, 4);
        STG_B(1, t3, 0);
        PH_MID(); MFMA_Q(4, 1, bfH); PH_END();

        STG_B(1, t3, 1);
        STG_A(1, t3, 0);
        asm volatile("s_waitcnt vmcnt(6)" ::: "memory");
        PH_MID(); MFMA_Q(4, 0, bfL); PH_END();
    }
    asm volatile("s_waitcnt vmcnt(0)" ::: "memory");

#undef STG_A
#undef STG_B
#undef LDS_A
#undef LDS_B
#undef MFMA_Q
#undef PH_MID
#undef PH_END

    int wr0 = rowBase + wrow * 128 + quad * 4;
    int wc0 = colBase + wcol * 64 + l15;
    // MODE 2: GELU -> bf16 row-major (FC1)
    #pragma unroll
    for (int mf = 0; mf < 8; ++mf) {
        #pragma unroll
        for (int nf = 0; nf < 4; ++nf) {
            int gc = wc0 + nf * 16;
            float bv = bias[gc];
            #pragma unroll
            for (int r = 0; r < 4; ++r) {
                int gr = wr0 + mf * 16 + r;
                float v = acc[mf][nf][r] + bv;
                float p = v * (1.59576912f + 0.07135481f * v * v);
                float e = __expf(-p);
                float gl = v * __builtin_amdgcn_rcpf(1.0f + e);
                o0[(size_t)gr * N + gc] = f2bf_fast(gl);
            }
        }
    }
}

// ---------------- flash attention (causal), bf16 in/out ----------------
// v2: SWAPPED QK^T — compute mfma(K_frag, Q_frag) so lane holds
// S[q=l15][k=nt*16+quad*4+r] (4 consecutive k per nt). P-stores become
// 4x ds_write_b64 per strip (was 16 scalar b16); rsum is a scalar per lane
// (q=l15) reduced with 2 shfl_xor (16,32); inv redistributed to the PV
// layout (q=quad*4+r) with 4 shfl. P_lds chunk swizzle uses EVEN XOR
// (chunk ^ (l15&14)) so the b128 PV read stays a contiguous ordered 16B.
// PV path, staging, barriers unchanged from the verified kernel.
__global__ __launch_bounds__(256) void flash_attn(
    const u16* __restrict__ Q, const u16* __restrict__ Kb,
    const u16* __restrict__ Vt, u16* __restrict__ O)
{
    __shared__ __attribute__((aligned(16))) u16 Ks[2][64 * 64];
    __shared__ __attribute__((aligned(16))) u16 Vs[2][64 * 64];
    __shared__ __attribute__((aligned(16))) u16 Pl[4][2][16][64];
    int tid = threadIdx.x;
    int lane = tid & 63, w = tid >> 6;
    int l15 = lane & 15, quad = lane >> 4;
    int bh = blockIdx.x;           // 0..63 (fastest-varying -> XCD = bh%8)
    int pp = blockIdx.y;           // 0..7
    int bb = bh >> 4, h = bh & 15;

    const u16* Kp0 = Kb + (size_t)bh * S_LEN * HDIM;
    const u16* Vp  = Vt + (size_t)bh * HDIM * S_LEN;

    int rstage = lane >> 3;                       // 0..7
    int cstage = ((lane & 7) ^ rstage) * 8;       // swizzled source chunk (u16 units)
    int vrow0  = w * 8 + rstage;                  // staging row within 32-row half

    int ms[2] = {pp, 15 - pp};
    int pb = 0;

    // prologue: stage K/V tile kt=0 into parity 0
    #pragma unroll
    for (int i = 0; i < 2; ++i) {
        int row = i * 32 + vrow0;
        gld_lds16(Kp0 + row * HDIM + cstage, &Ks[0][0] + i * 2048 + w * 512);
        gld_lds16(Vp + (size_t)row * S_LEN + cstage, &Vs[0][0] + i * 2048 + w * 512);
    }

    #pragma unroll 1
    for (int sel = 0; sel < 2; ++sel) {
        int m = ms[sel];
        int q0 = m * 128;

        const u16* Qp = Q + ((size_t)bh * S_LEN + q0 + w * 16) * HDIM;
        short8 aq0[2], aq1[2];
        #pragma unroll
        for (int ks = 0; ks < 2; ++ks) {
            aq0[ks] = *(const short8*)(Qp + l15 * HDIM + ks * 32 + quad * 8);
            aq1[ks] = *(const short8*)(Qp + 64 * HDIM + l15 * HDIM + ks * 32 + quad * 8);
        }

        floatx4 acc_o0[4] = {}, acc_o1[4] = {};
        float rs0 = 0.f, rs1 = 0.f;

        int KT = 2 * m + 2;   // K-tiles this macro (strip1 needs kt <= 2m+1)

        // sa[nt][r] = S[q=l15][k=nt*16+quad*4+r] (swapped layout)
        auto softmax_store = [&](floatx4 (&sa)[4], float& rs, int st, bool diag) {
            #pragma unroll
            for (int nt = 0; nt < 4; ++nt) {
                ushort4_t pk;
                #pragma unroll
                for (int r = 0; r < 4; ++r) {
                    float sv = sa[nt][r];           // scale already folded into Q
                    if (diag) {
                        int kc = nt * 16 + quad * 4 + r;
                        if (kc > w * 16 + l15) sv = -1e30f;
                    }
                    float pv = __expf(sv);          // fixed-max softmax; exp(-1e30)=0
                    rs += pv;
                    pk[r] = f2bf_fast(pv);
                }
                // store 4 consecutive k (8B) at chunk (nt*4+quad), even-XOR swizzled
                int chSw = (nt * 4 + quad) ^ (l15 & 14);
                *(ushort4_t*)(&Pl[w][st][l15][chSw * 4]) = pk;
            }
        };

        #pragma unroll 1
        for (int kt = 0; kt < KT; ++kt) {
            __syncthreads();   // tile kt (parity pb) resident; drain covered by prior phase
            int cur = pb;

            int nk = (kt + 1 < KT) ? (kt + 1) : ((sel < 1) ? 0 : -1);
            if (nk >= 0) {
                pb ^= 1;
                const u16* Kg = Kp0 + (size_t)nk * 64 * HDIM;
                const u16* Vg = Vp + nk * 64;
                u16* kb_ = &Ks[pb][0];
                u16* vb_ = &Vs[pb][0];
                #pragma unroll
                for (int i = 0; i < 2; ++i) {
                    int row = i * 32 + vrow0;
                    gld_lds16(Kg + row * HDIM + cstage, kb_ + i * 2048 + w * 512);
                    gld_lds16(Vg + (size_t)row * S_LEN + cstage, vb_ + i * 2048 + w * 512);
                }
            }

            const u16* kcur = &Ks[cur][0];
            const u16* vcur = &Vs[cur][0];

            bool a0 = (kt < KT - 1);      // strip0 active (kt <= 2m)

            // QK^T (swapped): D = K_tile . Q^T -> lane holds S[q=l15][k=..]
            floatx4 s0a[4] = {}, s1a[4] = {};
            __builtin_amdgcn_s_setprio(1);
            #pragma unroll
            for (int nt = 0; nt < 4; ++nt) {
                #pragma unroll
                for (int ks = 0; ks < 2; ++ks) {
                    int sw = ((ks * 4 + quad) ^ (l15 & 7)) * 8;
                    short8 bk = *(const short8*)(kcur + (nt * 16 + l15) * 64 + sw);
                    s0a[nt] = __builtin_amdgcn_mfma_f32_16x16x32_bf16(bk, aq0[ks], s0a[nt], 0, 0, 0);
                    s1a[nt] = __builtin_amdgcn_mfma_f32_16x16x32_bf16(bk, aq1[ks], s1a[nt], 0, 0, 0);
                }
            }
            __builtin_amdgcn_s_setprio(0);

            if (a0) softmax_store(s0a, rs0, 0, kt == KT - 2);
            softmax_store(s1a, rs1, 1, kt == KT - 1);

            // per-wave LDS round-trip: same-wave DS ordering, no barrier needed
            // A-frag read: P[l15][ks*32+quad*8 .. +7] = chunks {c0^M, c0^M+1}, ordered
            short8 pf0[2] = {}, pf1[2];
            if (a0) {
                #pragma unroll
                for (int ks = 0; ks < 2; ++ks) {
                    int pc = ((ks * 8 + quad * 2) ^ (l15 & 14)) * 4;
                    pf0[ks] = *(const short8*)(&Pl[w][0][l15][pc]);
                }
            }
            #pragma unroll
            for (int ks = 0; ks < 2; ++ks) {
                int pc = ((ks * 8 + quad * 2) ^ (l15 & 14)) * 4;
                pf1[ks] = *(const short8*)(&Pl[w][1][l15][pc]);
            }

            // PV: shared V-frag reads feed both strips (pf0 zeroed when inactive)
            __builtin_amdgcn_s_setprio(1);
            #pragma unroll
            for (int nt = 0; nt < 4; ++nt) {
                #pragma unroll
                for (int ks = 0; ks < 2; ++ks) {
                    int sw = ((ks * 4 + quad) ^ (l15 & 7)) * 8;
                    short8 bv = *(const short8*)(vcur + (nt * 16 + l15) * 64 + sw);
                    acc_o0[nt] = __builtin_amdgcn_mfma_f32_16x16x32_bf16(pf0[ks], bv, acc_o0[nt], 0, 0, 0);
                    acc_o1[nt] = __builtin_amdgcn_mfma_f32_16x16x32_bf16(pf1[ks], bv, acc_o1[nt], 0, 0, 0);
                }
            }
            __builtin_amdgcn_s_setprio(0);
        }

        // rsum: lane holds partial for q=l15 over its 16 k-cols; sum across quads
        rs0 += __shfl_xor(rs0, 16, 64);
        rs0 += __shfl_xor(rs0, 32, 64);
        rs1 += __shfl_xor(rs1, 16, 64);
        rs1 += __shfl_xor(rs1, 32, 64);
        float inv0 = 1.0f / rs0;   // valid for q = l15
        float inv1 = 1.0f / rs1;

        // redistribute to PV output layout (q = quad*4+r)
        float iv0[4], iv1[4];
        #pragma unroll
        for (int r = 0; r < 4; ++r) {
            iv0[r] = __shfl(inv0, quad * 4 + r, 64);
            iv1[r] = __shfl(inv1, quad * 4 + r, 64);
        }

        #pragma unroll
        for (int nt = 0; nt < 4; ++nt) {
            #pragma unroll
            for (int r = 0; r < 4; ++r) {
                int qr = q0 + w * 16 + quad * 4 + r;
                int hd = nt * 16 + l15;
                O[((size_t)bb * S_LEN + qr) * DMODEL + h * HDIM + hd] = f2bf(acc_o0[nt][r] * iv0[r]);
                O[((size_t)bb * S_LEN + qr + 64) * DMODEL + h * HDIM + hd] = f2bf(acc_o1[nt][r] * iv1[r]);
            }
        }
    }
}

extern "C" void kernel_launch(void* const* d_in, const int* in_sizes, int n_in,
                              void* d_out, int out_size, void* d_ws, size_t ws_size,
                              hipStream_t stream)
{
    const float* x    = (const float*)d_in[0];
    const float* ln1g = (const float*)d_in[2];
    const float* ln1b = (const float*)d_in[3];
    const float* wqkv = (const float*)d_in[4];
    const float* bqkv = (const float*)d_in[5];
    const float* wao  = (const float*)d_in[6];
    const float* bao  = (const float*)d_in[7];
    const float* ln2g = (const float*)d_in[8];
    const float* ln2b = (const float*)d_in[9];
    const float* wfc  = (const float*)d_in[10];
    const float* bfc  = (const float*)d_in[11];
    const float* wout = (const float*)d_in[12];
    const float* bout = (const float*)d_in[13];
    float* out = (float*)d_out;

    char* ws = (char*)d_ws;
    u16* wqkvT = (u16*)(ws + 0);          //  6.3 MB
    u16* waoT  = (u16*)(ws + 6291456);    //  2.1 MB
    u16* wfcT  = (u16*)(ws + 8388608);    //  8.4 MB
    u16* woutT = (u16*)(ws + 16777216);   //  8.4 MB
    u16* hb    = (u16*)(ws + 25165824);   // 16.8 MB: LN1 out; attn out; later h2
    u16* QKVb  = (u16*)(ws + 41943040);   // 50.3 MB: Q|K each 8.4M elements (V slot unused)
    u16* Vtb   = (u16*)(ws + 92274688);   // 16.8 MB: V^T (written directly by gemm_bt<0>)
    u16* Gb    = (u16*)(ws + 41943040);   // 67.1 MB: GELU out (QKV+Vt dead by then)

    u16* Qb   = QKVb;
    u16* Kbuf = QKVb + 8388608;

    // one launch: LN1 + all 4 weight transposes (all depend only on inputs)
    prep_kernel<<<dim3(20480), 256, 0, stream>>>(
        x, ln1g, ln1b, hb,
        wqkv, wqkvT, wao, waoT, wfc, wfcT, wout, woutT);

    gemm_bt<0><<<dim3(3072/128, 8192/128), 256, 0, stream>>>(
        hb, wqkvT, 8192, 3072, 1024, bqkv, nullptr, nullptr, QKVb, Vtb, nullptr);

    flash_attn<<<dim3(64, 8), 256, 0, stream>>>(Qb, Kbuf, Vtb, hb);

    gemm_bt<1><<<dim3(1024/128, 8192/128), 256, 0, stream>>>(
        hb, waoT, 8192, 1024, 1024, bao, x, out, nullptr, nullptr, nullptr);

    ln_kernel<<<8192, 256, 0, stream>>>(out, ln2g, ln2b, hb);

    gemm256<2><<<dim3(4096/256, 8192/256), 512, 0, stream>>>(
        hb, wfcT, 8192, 4096, 1024, bfc, Gb, nullptr);

    gemm_bt<3><<<dim3(1024/128, 8192/128), 256, 0, stream>>>(
        Gb, woutT, 8192, 1024, 4096, bout, out, out, nullptr, nullptr, nullptr);
}

// Round 11
// 476.692 us; speedup vs baseline: 1.0720x; 1.0074x over previous
//
#include <hip/hip_runtime.h>

typedef unsigned short u16;
typedef __attribute__((ext_vector_type(8))) short short8;
typedef __attribute__((ext_vector_type(4))) float floatx4;
typedef __attribute__((ext_vector_type(4))) unsigned short ushort4_t;

#define S_LEN 2048
#define DMODEL 1024
#define NHEAD 16
#define HDIM 64

__device__ __forceinline__ u16 f2bf(float f) {
    union { float f; unsigned u; } v; v.f = f;
    unsigned u = v.u;
    unsigned r = (u + 0x7fffu + ((u >> 16) & 1u)) >> 16;
    return (u16)r;
}

// round-half-up bf16 pack (2 VALU ops) — for GEMM-feeding intermediates
__device__ __forceinline__ u16 f2bf_fast(float f) {
    union { float f; unsigned u; } v; v.f = f;
    return (u16)((v.u + 0x8000u) >> 16);
}

__device__ __forceinline__ void gld_lds16(const u16* g, u16* l) {
    __builtin_amdgcn_global_load_lds((const __attribute__((address_space(1))) void*)g,
                                     (__attribute__((address_space(3))) void*)l,
                                     16, 0, 0);
}

// ---------------- LayerNorm -> bf16 (used standalone for LN2) ----------------
__global__ __launch_bounds__(256) void ln_kernel(
    const float* __restrict__ x, const float* __restrict__ g,
    const float* __restrict__ b, u16* __restrict__ out)
{
    int row = blockIdx.x;
    int tid = threadIdx.x;
    const float4* xr = (const float4*)(x + (size_t)row * DMODEL);
    float4 v = xr[tid];
    float s  = v.x + v.y + v.z + v.w;
    float s2 = v.x * v.x + v.y * v.y + v.z * v.z + v.w * v.w;
    #pragma unroll
    for (int off = 1; off < 64; off <<= 1) {
        s  += __shfl_xor(s, off, 64);
        s2 += __shfl_xor(s2, off, 64);
    }
    __shared__ float red[2][4];
    int w = tid >> 6, lane = tid & 63;
    if (lane == 0) { red[0][w] = s; red[1][w] = s2; }
    __syncthreads();
    s  = red[0][0] + red[0][1] + red[0][2] + red[0][3];
    s2 = red[1][0] + red[1][1] + red[1][2] + red[1][3];
    float mu  = s * (1.0f / DMODEL);
    float var = s2 * (1.0f / DMODEL) - mu * mu;
    float inv = rsqrtf(var + 1e-5f);
    const float4* gr = (const float4*)g;
    const float4* br = (const float4*)b;
    float4 gv = gr[tid], bv = br[tid];
    u16* o = out + (size_t)row * DMODEL + tid * 4;
    o[0] = f2bf((v.x - mu) * inv * gv.x + bv.x);
    o[1] = f2bf((v.y - mu) * inv * gv.y + bv.y);
    o[2] = f2bf((v.z - mu) * inv * gv.z + bv.z);
    o[3] = f2bf((v.w - mu) * inv * gv.w + bv.w);
}

// ---------------- prep: LN1 + 4 weight transposes in ONE launch ----------------
// Verified passing in r9/r10. Segments:
//  [0,8192): LN1 rows | [8192,11264): wqkv | [11264,12288): wao
//  [12288,16384): wfc | [16384,20480): wout
__global__ __launch_bounds__(256) void prep_kernel(
    const float* __restrict__ x, const float* __restrict__ g,
    const float* __restrict__ b, u16* __restrict__ out,
    const float* __restrict__ w0, u16* __restrict__ d0,
    const float* __restrict__ w1, u16* __restrict__ d1,
    const float* __restrict__ w2, u16* __restrict__ d2,
    const float* __restrict__ w3, u16* __restrict__ d3)
{
    int id = blockIdx.x;
    int tid = threadIdx.x;
    if (id < 8192) {
        // ---- LN1 ----
        int row = id;
        const float4* xr = (const float4*)(x + (size_t)row * DMODEL);
        float4 v = xr[tid];
        float s  = v.x + v.y + v.z + v.w;
        float s2 = v.x * v.x + v.y * v.y + v.z * v.z + v.w * v.w;
        #pragma unroll
        for (int off = 1; off < 64; off <<= 1) {
            s  += __shfl_xor(s, off, 64);
            s2 += __shfl_xor(s2, off, 64);
        }
        __shared__ float red[2][4];
        int w = tid >> 6, lane = tid & 63;
        if (lane == 0) { red[0][w] = s; red[1][w] = s2; }
        __syncthreads();
        s  = red[0][0] + red[0][1] + red[0][2] + red[0][3];
        s2 = red[1][0] + red[1][1] + red[1][2] + red[1][3];
        float mu  = s * (1.0f / DMODEL);
        float var = s2 * (1.0f / DMODEL) - mu * mu;
        float inv = rsqrtf(var + 1e-5f);
        const float4* gr = (const float4*)g;
        const float4* br = (const float4*)b;
        float4 gv = gr[tid], bv = br[tid];
        u16* o = out + (size_t)row * DMODEL + tid * 4;
        o[0] = f2bf((v.x - mu) * inv * gv.x + bv.x);
        o[1] = f2bf((v.y - mu) * inv * gv.y + bv.y);
        o[2] = f2bf((v.z - mu) * inv * gv.z + bv.z);
        o[3] = f2bf((v.w - mu) * inv * gv.w + bv.w);
        return;
    }
    // ---- weight transpose + cast: wt[n][k] = bf16(w[k][n]) ----
    id -= 8192;
    __shared__ float t[32][33];
    const float* w; u16* wt; int K, N, bx, by;
    if (id < 3072)      { w = w0; wt = d0; K = 1024; N = 3072; bx = id % 96;  by = id / 96;  }
    else if (id < 4096) { id -= 3072; w = w1; wt = d1; K = 1024; N = 1024; bx = id & 31;  by = id >> 5; }
    else if (id < 8192) { id -= 4096; w = w2; wt = d2; K = 1024; N = 4096; bx = id & 127; by = id >> 7; }
    else                { id -= 8192; w = w3; wt = d3; K = 4096; N = 1024; bx = id & 31;  by = id >> 5; }
    int n0 = bx * 32, k0 = by * 32;
    int xx = tid & 31, yy = tid >> 5;
    #pragma unroll
    for (int j = yy; j < 32; j += 8)
        t[j][xx] = w[(size_t)(k0 + j) * N + n0 + xx];
    __syncthreads();
    #pragma unroll
    for (int j = yy; j < 32; j += 8)
        wt[(size_t)(n0 + j) * K + k0 + xx] = f2bf(t[xx][j]);
}

// ---------------- legacy 128^2 GEMM (QKV / AO / FC2) ----------------
// Single-barrier double-buffered K-loop; staging pointers incremented.
// MODE 0: QKV -> Q (*0.125 folded) and K in [BH,S,64] at o0; V DIRECTLY
//         transposed [BH,64,S] into o1 with the s-axis SIGMA-SCRAMBLED within
//         each 64-tile (bits: g.b4=s.b3, g.b3=s.b2, g.b2=s.b4; b5,b1,b0 kept).
//         sigma makes flash's PV B-operand match the in-register P layout
//         (k-axis permuted identically in A and B => MFMA result unchanged).
// MODE 1/3: fout = C + bias + res (fp32)
// MODE 2: o0 = bf16(gelu(C + bias))
template<int MODE>
__global__ __launch_bounds__(256) void gemm_bt(
    const u16* __restrict__ A, const u16* __restrict__ BT,
    int M, int N, int K,
    const float* __restrict__ bias, const float* __restrict__ res,
    float* __restrict__ fout,
    u16* __restrict__ o0, u16* __restrict__ o1, u16* __restrict__ o2)
{
    __shared__ __attribute__((aligned(16))) u16 As[2][128 * 64];
    __shared__ __attribute__((aligned(16))) u16 Bs[2][128 * 64];
    int tid = threadIdx.x;
    int lane = tid & 63, w = tid >> 6;
    int wm = (w >> 1) * 64, wn = (w & 1) * 64;
    int l15 = lane & 15, quad = lane >> 4;
    int rowBase = blockIdx.y * 128, colBase = blockIdx.x * 128;

    floatx4 acc[4][4] = {};

    const u16* pa[4];
    const u16* pbt[4];
    int scb[4];
    #pragma unroll
    for (int i = 0; i < 4; ++i) {
        int c  = i * 256 + tid;
        int r  = c >> 3;
        int cs = ((c & 7) ^ (r & 7)) * 8;            // swizzled source chunk
        pa[i]  = A  + (size_t)(rowBase + r) * K + cs;
        pbt[i] = BT + (size_t)(colBase + r) * K + cs;
        scb[i] = (i * 256 + (tid & 0xC0)) * 8;       // wave-uniform LDS base
    }

    int KT = K >> 6;

    #pragma unroll
    for (int i = 0; i < 4; ++i) {
        gld_lds16(pa[i],  &As[0][0] + scb[i]);
        gld_lds16(pbt[i], &Bs[0][0] + scb[i]);
    }

    for (int kt = 0; kt < KT; ++kt) {
        __syncthreads();

        if (kt + 1 < KT) {
            u16* abuf = &As[(kt + 1) & 1][0];
            u16* bbuf = &Bs[(kt + 1) & 1][0];
            #pragma unroll
            for (int i = 0; i < 4; ++i) {
                pa[i]  += 64;
                pbt[i] += 64;
                gld_lds16(pa[i],  abuf + scb[i]);
                gld_lds16(pbt[i], bbuf + scb[i]);
            }
        }

        const u16* as = &As[kt & 1][0];
        const u16* bs = &Bs[kt & 1][0];
        #pragma unroll
        for (int ks = 0; ks < 2; ++ks) {
            int sw = (((ks * 4 + quad) ^ (l15 & 7))) * 8;
            short8 af[4], bf[4];
            #pragma unroll
            for (int im = 0; im < 4; ++im)
                af[im] = *(const short8*)(as + (wm + im * 16 + l15) * 64 + sw);
            #pragma unroll
            for (int in = 0; in < 4; ++in)
                bf[in] = *(const short8*)(bs + (wn + in * 16 + l15) * 64 + sw);
            #pragma unroll
            for (int im = 0; im < 4; ++im)
                #pragma unroll
                for (int in = 0; in < 4; ++in)
                    acc[im][in] = __builtin_amdgcn_mfma_f32_16x16x32_bf16(af[im], bf[in], acc[im][in], 0, 0, 0);
        }
    }

    // epilogue
    if (MODE == 0) {
        int t = colBase >> 10;                 // uniform per block (q/k/v)
        int cb1023 = colBase & 1023;
        if (t == 2) {
            // V: write directly transposed [BH,64,S]; r=0..3 are consecutive s.
            // Store position sigma^-1(s) within each 64-tile (4-alignment kept).
            #pragma unroll
            for (int im = 0; im < 4; ++im) {
                int gr0 = rowBase + wm + im * 16 + quad * 4;
                int bb2 = gr0 >> 11, ss = gr0 & 2047;
                int sl = ss & 63;
                int ssg = (ss & ~63) | (sl & 35)
                        | (((sl >> 3) & 1) << 4)
                        | (((sl >> 2) & 1) << 3)
                        | (((sl >> 4) & 1) << 2);
                #pragma unroll
                for (int in = 0; in < 4; ++in) {
                    int gc = colBase + wn + in * 16 + l15;
                    int rr = cb1023 + wn + in * 16 + l15;
                    int hh = rr >> 6, hd = rr & 63;
                    float bv = bias[gc];
                    ushort4_t pk;
                    pk.x = f2bf_fast(acc[im][in][0] + bv);
                    pk.y = f2bf_fast(acc[im][in][1] + bv);
                    pk.z = f2bf_fast(acc[im][in][2] + bv);
                    pk.w = f2bf_fast(acc[im][in][3] + bv);
                    *(ushort4_t*)(o1 + ((size_t)(bb2 * NHEAD + hh) * HDIM + hd) * S_LEN + ssg) = pk;
                }
            }
        } else {
            u16* qb = o0 + (size_t)t * 8388608;    // 8192*1024 elements per tensor
            float sc = (t == 0) ? 0.125f : 1.0f;   // fold softmax 1/sqrt(64) into Q
            #pragma unroll
            for (int im = 0; im < 4; ++im) {
                #pragma unroll
                for (int in = 0; in < 4; ++in) {
                    #pragma unroll
                    for (int r = 0; r < 4; ++r) {
                        int gr = rowBase + wm + im * 16 + quad * 4 + r;
                        int gc = colBase + wn + in * 16 + l15;
                        float v = (acc[im][in][r] + bias[gc]) * sc;
                        int rr = cb1023 + wn + in * 16 + l15;
                        int hh = rr >> 6, hd = rr & 63;
                        int bb2 = gr >> 11, ss = gr & 2047;
                        qb[(((size_t)(bb2 * NHEAD + hh) * S_LEN + ss) * HDIM) + hd] = f2bf_fast(v);
                    }
                }
            }
        }
    } else {
        #pragma unroll
        for (int im = 0; im < 4; ++im) {
            #pragma unroll
            for (int in = 0; in < 4; ++in) {
                #pragma unroll
                for (int r = 0; r < 4; ++r) {
                    int gr = rowBase + wm + im * 16 + quad * 4 + r;
                    int gc = colBase + wn + in * 16 + l15;
                    float v = acc[im][in][r] + bias[gc];
                    if (MODE == 2) {
                        float p = v * (1.59576912f + 0.07135481f * v * v);
                        float e = __expf(-p);
                        float gl = v * __builtin_amdgcn_rcpf(1.0f + e);
                        o0[(size_t)gr * N + gc] = f2bf_fast(gl);
                    } else {
                        fout[(size_t)gr * N + gc] = v + res[(size_t)gr * N + gc];
                    }
                }
            }
        }
    }
}

// ---------------- 256^2 8-phase GEMM (FC1 only: grid 16x32 = 2 full rounds) ----------------
// Verified passing in rounds 3/5/8/9/10.
template<int MODE>
__global__ __launch_bounds__(512, 2) void gemm256(
    const u16* __restrict__ A, const u16* __restrict__ BT,
    int M, int N, int K,
    const float* __restrict__ bias,
    u16* __restrict__ o0, u16* __restrict__ o1)
{
    __shared__ __attribute__((aligned(16))) u16 As[2][2][128 * 64];
    __shared__ __attribute__((aligned(16))) u16 Bs[2][2][128 * 64];
    int tid = threadIdx.x;
    int lane = tid & 63, w = tid >> 6;
    int wrow = w >> 2, wcol = w & 3;
    int l15 = lane & 15, quad = lane >> 4;
    int rowBase = blockIdx.y * 256, colBase = blockIdx.x * 256;
    int nrb = (wcol & 1) * 64;

    int swz[2] = { (quad ^ (l15 & 7)) * 8, ((4 + quad) ^ (l15 & 7)) * 8 };

    int cid0 = tid, cid1 = 512 + tid;
    int r0 = cid0 >> 3, r1 = cid1 >> 3;
    unsigned cs0 = (unsigned)(((cid0 & 7) ^ (r0 & 7)) * 8);
    unsigned cs1 = (unsigned)(((cid1 & 7) ^ (r1 & 7)) * 8);
    unsigned aoff0 = (unsigned)((rowBase + r0) * K) + cs0;
    unsigned aoff1 = (unsigned)((rowBase + r1) * K) + cs1;
    unsigned boff0 = (unsigned)((colBase + r0) * K) + cs0;
    unsigned boff1 = (unsigned)((colBase + r1) * K) + cs1;
    unsigned ldo0 = (unsigned)(cid0 * 8), ldo1 = (unsigned)(cid1 * 8);
    unsigned hK = (unsigned)(128 * K);

    floatx4 acc[8][4] = {};
    short8 af[4][2], bfL[2][2], bfH[2][2];

    int KT = K >> 6;

#define STG_A(db, tt, h) do { unsigned tb_ = (unsigned)(tt) * 64u + (h) * hK;      \
    gld_lds16(A + aoff0 + tb_, &As[db][h][0] + ldo0);                              \
    gld_lds16(A + aoff1 + tb_, &As[db][h][0] + ldo1); } while (0)
#define STG_B(db, tt, h) do { unsigned tb_ = (unsigned)(tt) * 64u + (h) * hK;      \
    gld_lds16(BT + boff0 + tb_, &Bs[db][h][0] + ldo0);                             \
    gld_lds16(BT + boff1 + tb_, &Bs[db][h][0] + ldo1); } while (0)
#define LDS_A(buf, MFB) do { const u16* ap_ = &As[buf][wrow][0];                   \
    _Pragma("unroll") for (int m_ = 0; m_ < 4; ++m_) {                             \
      af[m_][0] = *(const short8*)(ap_ + (((MFB) + m_) * 16 + l15) * 64 + swz[0]); \
      af[m_][1] = *(const short8*)(ap_ + (((MFB) + m_) * 16 + l15) * 64 + swz[1]); } } while (0)
#define LDS_B(buf, NFP, dst) do { const u16* bp_ = &Bs[buf][wcol >> 1][0];         \
    _Pragma("unroll") for (int n_ = 0; n_ < 2; ++n_) {                             \
      dst[n_][0] = *(const short8*)(bp_ + (nrb + ((NFP) * 2 + n_) * 16 + l15) * 64 + swz[0]); \
      dst[n_][1] = *(const short8*)(bp_ + (nrb + ((NFP) * 2 + n_) * 16 + l15) * 64 + swz[1]); } } while (0)
#define MFMA_Q(MFB, NFP, bsrc) do { __builtin_amdgcn_s_setprio(1);                 \
    _Pragma("unroll") for (int m_ = 0; m_ < 4; ++m_)                               \
    _Pragma("unroll") for (int n_ = 0; n_ < 2; ++n_) {                             \
      acc[(MFB) + m_][(NFP) * 2 + n_] = __builtin_amdgcn_mfma_f32_16x16x32_bf16(af[m_][0], bsrc[n_][0], acc[(MFB) + m_][(NFP) * 2 + n_], 0, 0, 0); \
      acc[(MFB) + m_][(NFP) * 2 + n_] = __builtin_amdgcn_mfma_f32_16x16x32_bf16(af[m_][1], bsrc[n_][1], acc[(MFB) + m_][(NFP) * 2 + n_], 0, 0, 0); } \
    __builtin_amdgcn_s_setprio(0); } while (0)
#define PH_MID() do { __builtin_amdgcn_sched_barrier(0);                           \
    __builtin_amdgcn_s_barrier();                                                  \
    asm volatile("s_waitcnt lgkmcnt(0)" ::: "memory");                             \
    __builtin_amdgcn_sched_barrier(0); } while (0)
#define PH_END() do { __builtin_amdgcn_sched_barrier(0);                           \
    __builtin_amdgcn_s_barrier(); } while (0)

    STG_A(0, 0, 0); STG_A(0, 0, 1);
    STG_B(0, 0, 0); STG_B(0, 0, 1);
    STG_B(1, 1, 0); STG_B(1, 1, 1);
    STG_A(1, 1, 0);
    asm volatile("s_waitcnt vmcnt(6)" ::: "memory");
    __builtin_amdgcn_s_barrier();

    for (int t = 0; t < KT; t += 2) {
        int t2 = (t + 2 < KT) ? t + 2 : KT - 1;
        int t3 = (t + 3 < KT) ? t + 3 : KT - 1;

        LDS_A(0, 0); LDS_B(0, 0, bfL);
        STG_A(1, t + 1, 1);
        asm volatile("s_waitcnt lgkmcnt(8)" ::: "memory");
        PH_MID(); MFMA_Q(0, 0, bfL); PH_END();

        LDS_B(0, 1, bfH);
        PH_MID(); MFMA_Q(0, 1, bfH); PH_END();

        LDS_A(0, 4);
        STG_B(0, t2, 0);
        PH_MID(); MFMA_Q(4, 1, bfH); PH_END();

        STG_B(0, t2, 1);
        STG_A(0, t2, 0);
        asm volatile("s_waitcnt vmcnt(6)" ::: "memory");
        PH_MID(); MFMA_Q(4, 0, bfL); PH_END();

        LDS_A(1, 0); LDS_B(1, 0, bfL);
        STG_A(0, t2, 1);
        asm volatile("s_waitcnt lgkmcnt(8)" ::: "memory");
        PH_MID(); MFMA_Q(0, 0, bfL); PH_END();

        LDS_B(1, 1, bfH);
        PH_MID(); MFMA_Q(0, 1, bfH); PH_END();

        LDS_A(1, 4);
        STG_B(1, t3, 0);
        PH_MID(); MFMA_Q(4, 1, bfH); PH_END();

        STG_B(1, t3, 1);
        STG_A(1, t3, 0);
        asm volatile("s_waitcnt vmcnt(6)" ::: "memory");
        PH_MID(); MFMA_Q(4, 0, bfL); PH_END();
    }
    asm volatile("s_waitcnt vmcnt(0)" ::: "memory");

#undef STG_A
#undef STG_B
#undef LDS_A
#undef LDS_B
#undef MFMA_Q
#undef PH_MID
#undef PH_END

    int wr0 = rowBase + wrow * 128 + quad * 4;
    int wc0 = colBase + wcol * 64 + l15;
    // MODE 2: GELU -> bf16 row-major (FC1)
    #pragma unroll
    for (int mf = 0; mf < 8; ++mf) {
        #pragma unroll
        for (int nf = 0; nf < 4; ++nf) {
            int gc = wc0 + nf * 16;
            float bv = bias[gc];
            #pragma unroll
            for (int r = 0; r < 4; ++r) {
                int gr = wr0 + mf * 16 + r;
                float v = acc[mf][nf][r] + bv;
                float p = v * (1.59576912f + 0.07135481f * v * v);
                float e = __expf(-p);
                float gl = v * __builtin_amdgcn_rcpf(1.0f + e);
                o0[(size_t)gr * N + gc] = f2bf_fast(gl);
            }
        }
    }
}

// ---------------- flash attention (causal), bf16 in/out ----------------
// v3: P stays IN REGISTERS. Swapped QK^T gives lane P[q=l15][s=16nt+4quad+r];
// with the k-axis of PV permuted by sigma (s=32ks+8quad+4h+r' -> 32ks+16h+
// 4quad+r', applied to BOTH operands: A = register concat {pk[2ks],pk[2ks+1]},
// B = V with sigma-scrambled s (done at the V-writer)), the MFMA result is
// unchanged. Removes 8 ds_write_b64 + 4 ds_read_b128 per iter and the 16KB
// Pl buffer -> LDS 32KB -> 5 blocks/CU (was 3). Staging/QK^T/output unchanged.
__global__ __launch_bounds__(256) void flash_attn(
    const u16* __restrict__ Q, const u16* __restrict__ Kb,
    const u16* __restrict__ Vt, u16* __restrict__ O)
{
    __shared__ __attribute__((aligned(16))) u16 Ks[2][64 * 64];
    __shared__ __attribute__((aligned(16))) u16 Vs[2][64 * 64];
    int tid = threadIdx.x;
    int lane = tid & 63, w = tid >> 6;
    int l15 = lane & 15, quad = lane >> 4;
    int bh = blockIdx.x;           // 0..63 (fastest-varying -> XCD = bh%8)
    int pp = blockIdx.y;           // 0..7
    int bb = bh >> 4, h = bh & 15;

    const u16* Kp0 = Kb + (size_t)bh * S_LEN * HDIM;
    const u16* Vp  = Vt + (size_t)bh * HDIM * S_LEN;

    int rstage = lane >> 3;                       // 0..7
    int cstage = ((lane & 7) ^ rstage) * 8;       // swizzled source chunk (u16 units)
    int vrow0  = w * 8 + rstage;                  // staging row within 32-row half

    int ms[2] = {pp, 15 - pp};
    int pb = 0;

    // prologue: stage K/V tile kt=0 into parity 0
    #pragma unroll
    for (int i = 0; i < 2; ++i) {
        int row = i * 32 + vrow0;
        gld_lds16(Kp0 + row * HDIM + cstage, &Ks[0][0] + i * 2048 + w * 512);
        gld_lds16(Vp + (size_t)row * S_LEN + cstage, &Vs[0][0] + i * 2048 + w * 512);
    }

    #pragma unroll 1
    for (int sel = 0; sel < 2; ++sel) {
        int m = ms[sel];
        int q0 = m * 128;

        const u16* Qp = Q + ((size_t)bh * S_LEN + q0 + w * 16) * HDIM;
        short8 aq0[2], aq1[2];
        #pragma unroll
        for (int ks = 0; ks < 2; ++ks) {
            aq0[ks] = *(const short8*)(Qp + l15 * HDIM + ks * 32 + quad * 8);
            aq1[ks] = *(const short8*)(Qp + 64 * HDIM + l15 * HDIM + ks * 32 + quad * 8);
        }

        floatx4 acc_o0[4] = {}, acc_o1[4] = {};
        float rs0 = 0.f, rs1 = 0.f;

        int KT = 2 * m + 2;   // K-tiles this macro (strip1 needs kt <= 2m+1)

        // sa[nt][r] = S[q=l15][s=nt*16+quad*4+r]; pack P as 2 u32 (4 bf16) per nt
        auto softmax_pack = [&](floatx4 (&sa)[4], float& rs, unsigned (&pA)[4][2], bool diag) {
            #pragma unroll
            for (int nt = 0; nt < 4; ++nt) {
                u16 pk[4];
                #pragma unroll
                for (int r = 0; r < 4; ++r) {
                    float sv = sa[nt][r];           // scale already folded into Q
                    if (diag) {
                        int kc = nt * 16 + quad * 4 + r;
                        if (kc > w * 16 + l15) sv = -1e30f;
                    }
                    float pv = __expf(sv);          // fixed-max softmax; exp(-1e30)=0
                    rs += pv;
                    pk[r] = f2bf_fast(pv);
                }
                pA[nt][0] = (unsigned)pk[0] | ((unsigned)pk[1] << 16);
                pA[nt][1] = (unsigned)pk[2] | ((unsigned)pk[3] << 16);
            }
        };

        #pragma unroll 1
        for (int kt = 0; kt < KT; ++kt) {
            __syncthreads();   // tile kt (parity pb) resident; drain covered by prior phase
            int cur = pb;

            int nk = (kt + 1 < KT) ? (kt + 1) : ((sel < 1) ? 0 : -1);
            if (nk >= 0) {
                pb ^= 1;
                const u16* Kg = Kp0 + (size_t)nk * 64 * HDIM;
                const u16* Vg = Vp + nk * 64;
                u16* kb_ = &Ks[pb][0];
                u16* vb_ = &Vs[pb][0];
                #pragma unroll
                for (int i = 0; i < 2; ++i) {
                    int row = i * 32 + vrow0;
                    gld_lds16(Kg + row * HDIM + cstage, kb_ + i * 2048 + w * 512);
                    gld_lds16(Vg + (size_t)row * S_LEN + cstage, vb_ + i * 2048 + w * 512);
                }
            }

            const u16* kcur = &Ks[cur][0];
            const u16* vcur = &Vs[cur][0];

            bool a0 = (kt < KT - 1);      // strip0 active (kt <= 2m)

            // QK^T (swapped): lane holds S[q=l15][s=nt*16+quad*4+r]
            floatx4 s0a[4] = {}, s1a[4] = {};
            __builtin_amdgcn_s_setprio(1);
            #pragma unroll
            for (int nt = 0; nt < 4; ++nt) {
                #pragma unroll
                for (int ks = 0; ks < 2; ++ks) {
                    int sw = ((ks * 4 + quad) ^ (l15 & 7)) * 8;
                    short8 bk = *(const short8*)(kcur + (nt * 16 + l15) * 64 + sw);
                    s0a[nt] = __builtin_amdgcn_mfma_f32_16x16x32_bf16(bk, aq0[ks], s0a[nt], 0, 0, 0);
                    s1a[nt] = __builtin_amdgcn_mfma_f32_16x16x32_bf16(bk, aq1[ks], s1a[nt], 0, 0, 0);
                }
            }
            __builtin_amdgcn_s_setprio(0);

            unsigned pA0[4][2], pA1[4][2];
            if (a0) softmax_pack(s0a, rs0, pA0, kt == KT - 2);
            softmax_pack(s1a, rs1, pA1, kt == KT - 1);

            // A-operand = register concat under sigma: pf[ks] = {pk[2ks], pk[2ks+1]}
            short8 pf0[2] = {}, pf1[2];
            #pragma unroll
            for (int ks = 0; ks < 2; ++ks) {
                union { unsigned u[4]; short8 s; } c0, c1;
                if (a0) {
                    c0.u[0] = pA0[2 * ks][0]; c0.u[1] = pA0[2 * ks][1];
                    c0.u[2] = pA0[2 * ks + 1][0]; c0.u[3] = pA0[2 * ks + 1][1];
                    pf0[ks] = c0.s;
                }
                c1.u[0] = pA1[2 * ks][0]; c1.u[1] = pA1[2 * ks][1];
                c1.u[2] = pA1[2 * ks + 1][0]; c1.u[3] = pA1[2 * ks + 1][1];
                pf1[ks] = c1.s;
            }

            // PV: V pre-scrambled by sigma at the writer; read addressing unchanged
            __builtin_amdgcn_s_setprio(1);
            #pragma unroll
            for (int nt = 0; nt < 4; ++nt) {
                #pragma unroll
                for (int ks = 0; ks < 2; ++ks) {
                    int sw = ((ks * 4 + quad) ^ (l15 & 7)) * 8;
                    short8 bv = *(const short8*)(vcur + (nt * 16 + l15) * 64 + sw);
                    acc_o0[nt] = __builtin_amdgcn_mfma_f32_16x16x32_bf16(pf0[ks], bv, acc_o0[nt], 0, 0, 0);
                    acc_o1[nt] = __builtin_amdgcn_mfma_f32_16x16x32_bf16(pf1[ks], bv, acc_o1[nt], 0, 0, 0);
                }
            }
            __builtin_amdgcn_s_setprio(0);
        }

        // rsum: lane holds partial for q=l15 over its 16 k-cols; sum across quads
        rs0 += __shfl_xor(rs0, 16, 64);
        rs0 += __shfl_xor(rs0, 32, 64);
        rs1 += __shfl_xor(rs1, 16, 64);
        rs1 += __shfl_xor(rs1, 32, 64);
        float inv0 = 1.0f / rs0;   // valid for q = l15
        float inv1 = 1.0f / rs1;

        // redistribute to PV output layout (q = quad*4+r)
        float iv0[4], iv1[4];
        #pragma unroll
        for (int r = 0; r < 4; ++r) {
            iv0[r] = __shfl(inv0, quad * 4 + r, 64);
            iv1[r] = __shfl(inv1, quad * 4 + r, 64);
        }

        #pragma unroll
        for (int nt = 0; nt < 4; ++nt) {
            #pragma unroll
            for (int r = 0; r < 4; ++r) {
                int qr = q0 + w * 16 + quad * 4 + r;
                int hd = nt * 16 + l15;
                O[((size_t)bb * S_LEN + qr) * DMODEL + h * HDIM + hd] = f2bf(acc_o0[nt][r] * iv0[r]);
                O[((size_t)bb * S_LEN + qr + 64) * DMODEL + h * HDIM + hd] = f2bf(acc_o1[nt][r] * iv1[r]);
            }
        }
    }
}

extern "C" void kernel_launch(void* const* d_in, const int* in_sizes, int n_in,
                              void* d_out, int out_size, void* d_ws, size_t ws_size,
                              hipStream_t stream)
{
    const float* x    = (const float*)d_in[0];
    const float* ln1g = (const float*)d_in[2];
    const float* ln1b = (const float*)d_in[3];
    const float* wqkv = (const float*)d_in[4];
    const float* bqkv = (const float*)d_in[5];
    const float* wao  = (const float*)d_in[6];
    const float* bao  = (const float*)d_in[7];
    const float* ln2g = (const float*)d_in[8];
    const float* ln2b = (const float*)d_in[9];
    const float* wfc  = (const float*)d_in[10];
    const float* bfc  = (const float*)d_in[11];
    const float* wout = (const float*)d_in[12];
    const float* bout = (const float*)d_in[13];
    float* out = (float*)d_out;

    char* ws = (char*)d_ws;
    u16* wqkvT = (u16*)(ws + 0);          //  6.3 MB
    u16* waoT  = (u16*)(ws + 6291456);    //  2.1 MB
    u16* wfcT  = (u16*)(ws + 8388608);    //  8.4 MB
    u16* woutT = (u16*)(ws + 16777216);   //  8.4 MB
    u16* hb    = (u16*)(ws + 25165824);   // 16.8 MB: LN1 out; attn out; later h2
    u16* QKVb  = (u16*)(ws + 41943040);   // 50.3 MB: Q|K each 8.4M elements (V slot unused)
    u16* Vtb   = (u16*)(ws + 92274688);   // 16.8 MB: V^T sigma-scrambled (written by gemm_bt<0>)
    u16* Gb    = (u16*)(ws + 41943040);   // 67.1 MB: GELU out (QKV+Vt dead by then)

    u16* Qb   = QKVb;
    u16* Kbuf = QKVb + 8388608;

    // one launch: LN1 + all 4 weight transposes (all depend only on inputs)
    prep_kernel<<<dim3(20480), 256, 0, stream>>>(
        x, ln1g, ln1b, hb,
        wqkv, wqkvT, wao, waoT, wfc, wfcT, wout, woutT);

    gemm_bt<0><<<dim3(3072/128, 8192/128), 256, 0, stream>>>(
        hb, wqkvT, 8192, 3072, 1024, bqkv, nullptr, nullptr, QKVb, Vtb, nullptr);

    flash_attn<<<dim3(64, 8), 256, 0, stream>>>(Qb, Kbuf, Vtb, hb);

    gemm_bt<1><<<dim3(1024/128, 8192/128), 256, 0, stream>>>(
        hb, waoT, 8192, 1024, 1024, bao, x, out, nullptr, nullptr, nullptr);

    ln_kernel<<<8192, 256, 0, stream>>>(out, ln2g, ln2b, hb);

    gemm256<2><<<dim3(4096/256, 8192/256), 512, 0, stream>>>(
        hb, wfcT, 8192, 4096, 1024, bfc, Gb, nullptr);

    gemm_bt<3><<<dim3(1024/128, 8192/128), 256, 0, stream>>>(
        Gb, woutT, 8192, 1024, 4096, bout, out, out, nullptr, nullptr, nullptr);
}